// Round 16
// baseline (69.271 us; speedup 1.0000x reference)
//
#include <hip/hip_runtime.h>

#define TT 1024
#define NH 16
#define DD 128
#define WIN 256
#define SW 288            // stored band width (18 x 16); S layout: [b][t][h][SW]
#define SCALE 0.08838834764831845f

typedef float f32x4 __attribute__((ext_vector_type(4)));
typedef short s16x8 __attribute__((ext_vector_type(8)));

__device__ __forceinline__ ushort f2bf(float x) {
  union { float f; unsigned u; } v; v.f = x;
  unsigned r = v.u + 0x7FFFu + ((v.u >> 16) & 1u);
  return (ushort)(r >> 16);
}
__device__ __forceinline__ float bf2f(ushort u) {
  union { unsigned u; float f; } v; v.u = ((unsigned)u) << 16; return v.f;
}
__device__ __forceinline__ float bflo(uint p) {
  union { unsigned u; float f; } v; v.u = p << 16; return v.f;
}
__device__ __forceinline__ float bfhi(uint p) {
  union { unsigned u; float f; } v; v.u = p & 0xFFFF0000u; return v.f;
}

// ---------- KA+: 1024 QK jobs | 512 v8 | 512 mqA | 64 kw (all prep inside) ----------
__global__ __launch_bounds__(256, 4)
void ka_qk(const float* __restrict__ q, const float* __restrict__ k,
           const float* __restrict__ v,
           const float* __restrict__ w_pre, const float* __restrict__ w_post,
           const float* __restrict__ qw1_pre, const float* __restrict__ qw2_pre,
           const float* __restrict__ qdd_pre,
           const float* __restrict__ kw1_pre, const float* __restrict__ kw2_pre,
           const float* __restrict__ kdd_pre,
           const float* __restrict__ qw1_post, const float* __restrict__ qw2_post,
           const float* __restrict__ qdd_post,
           const float* __restrict__ kw1_post, const float* __restrict__ kw2_post,
           const float* __restrict__ kdd_post,
           ushort* __restrict__ S, ushort* __restrict__ v8,
           uint* __restrict__ mqA, uint* __restrict__ kwsT2)
{
  const int g = blockIdx.x;                    // 2112
  const int tid = threadIdx.x;
  __shared__ float sPool[64 * 132];            // 33.8 KB shared by all branches

  if (g < 1024) {
    // ---- QK band GEMM per (b,h,32-t tile) -> S[b][t][h][*] bf16 ----
    float* strip = sPool;                      // 16*300 floats (19.2 KB)
    const int job = (g & 7) * 128 + (g >> 3);  // XCD swizzle: XCD_i owns (b0..,h 4i..)
    const int b = job >> 9, h = (job >> 5) & 15, tt = job & 31;
    const int t0 = tt * 32;
    const int s0 = (t0 >= WIN) ? t0 - WIN : 0;
    const int lane = tid & 63, wv = tid >> 6;

    // stage this block's 32 q rows (fp32, coalesced) and build fragments w/ SCALE
    {
      const float* qsrc = q + (((long long)(b * TT + t0)) * NH + h) * DD;
#pragma unroll
      for (int it = 0; it < 4; ++it) {
        int idx = tid + it * 256;              // 1024 float4 = 32 rows x 32
        int r = idx >> 5, cg = idx & 31;
        float4 x = *(const float4*)(qsrc + (long long)r * (NH * DD) + cg * 4);
        *(float4*)(&sPool[r * 132 + cg * 4]) = x;
      }
    }
    __syncthreads();
    s16x8 qa[2][4];
    {
      const int ko = lane >> 4;
#pragma unroll
      for (int rt2 = 0; rt2 < 2; ++rt2) {
        int rloc = rt2 * 16 + (lane & 15);
#pragma unroll
        for (int kk = 0; kk < 4; ++kk) {
          union { ushort u[8]; s16x8 v; } pk;
#pragma unroll
          for (int e = 0; e < 8; ++e)
            pk.u[e] = f2bf(sPool[rloc * 132 + kk * 32 + ko * 8 + e] * SCALE);
          qa[rt2][kk] = pk.v;
        }
      }
    }
    __syncthreads();                           // sPool now free for strip

    for (int rt = 0; rt < 2; ++rt) {
      const int tlo = t0 + rt * 16;
      int cl0 = tlo - (WIN - 1) - s0; if (cl0 < 0) cl0 = 0;
      const int chi = tlo + 15 - s0;
      const int stb = cl0 >> 4;
      const int nst = (chi >> 4) - stb + 1;
      for (int sti = wv; sti < nst; sti += 4) {
        const int cst = (stb + sti) * 16;
        const int scol = s0 + cst + (lane & 15);
        const int ko = lane >> 4;
        // k read direct fp32: 16 s-rows x full 128B d-line per kk (all bytes used)
        const float* kf = k + (((long long)(b * TT + scol)) * NH + h) * DD + ko * 8;
        f32x4 acc = {0.f, 0.f, 0.f, 0.f};
#pragma unroll
        for (int kk = 0; kk < 4; ++kk) {
          float4 x = *(const float4*)(kf + kk * 32);
          float4 y = *(const float4*)(kf + kk * 32 + 4);
          union { ushort u[8]; s16x8 v; } pk;
          pk.u[0]=f2bf(x.x); pk.u[1]=f2bf(x.y); pk.u[2]=f2bf(x.z); pk.u[3]=f2bf(x.w);
          pk.u[4]=f2bf(y.x); pk.u[5]=f2bf(y.y); pk.u[6]=f2bf(y.z); pk.u[7]=f2bf(y.w);
          acc = __builtin_amdgcn_mfma_f32_16x16x32_bf16(qa[rt][kk], pk.v, acc, 0, 0, 0);
        }
        const int r0 = (lane >> 4) * 4;
#pragma unroll
        for (int j = 0; j < 4; ++j)
          strip[(r0 + j) * 300 + cst + (lane & 15)] = acc[j];
      }
      __syncthreads();
#pragma unroll
      for (int it = 0; it < 3; ++it) {
        int idx = tid + it * 256;
        if (idx < 16 * 36) {
          int r = idx / 36, sg = idx % 36;
          union { ushort u[8]; uint4 v; } pk;
#pragma unroll
          for (int e = 0; e < 8; ++e)
            pk.u[e] = f2bf(strip[r * 300 + sg * 8 + e]);
          *(uint4*)(S + (((long long)(b * TT + tlo + r)) * NH + h) * SW + sg * 8) = pk.v;
        }
      }
      __syncthreads();
    }
  } else if (g < 1536) {
    // ---- v fp32 -> v8 bf16 [b][h][soct128][d][8] ----
    const int bidx = g - 1024;
    const int st = bidx & 15, h = (bidx >> 4) & 15, b = bidx >> 8;
    const int s0 = st * 64;
#pragma unroll
    for (int it = 0; it < 8; ++it) {
      int idx = tid + it * 256;
      int r = idx >> 5, cg = idx & 31;
      float4 x = *(const float4*)(v + (((long long)(b * TT + s0 + r)) * NH + h) * DD + cg * 4);
      *(float4*)(&sPool[r * 132 + cg * 4]) = x;
    }
    __syncthreads();
#pragma unroll
    for (int it = 0; it < 4; ++it) {
      int idx = tid + it * 256;
      int d = idx & 127, so = idx >> 7;
      union { ushort u[8]; uint4 v; } pk;
#pragma unroll
      for (int e = 0; e < 8; ++e)
        pk.u[e] = f2bf(sPool[(so * 8 + e) * 132 + d]);
      *(uint4*)(v8 + ((((long long)(b * NH + h)) * 128 + st * 8 + so) * DD + d) * 8) = pk.v;
    }
  } else if (g < 2048) {
    // ---- mqA: (pass,b) x 8 t's. Mq_rest = W + qw1*qw2^T + diag(qdd) ----
    ushort* sH = (ushort*)sPool;               // [8][256]
    const int gg = g - 1536;
    const int tgrp = gg & 127, b = (gg >> 7) & 1, pass = gg >> 8;
    const int t0 = tgrp * 8;
    const float* W   = pass ? w_post   : w_pre;
    const float* QW1 = pass ? qw1_post : qw1_pre;
    const float* QW2 = pass ? qw2_post : qw2_pre;
    const float* QDD = pass ? qdd_post : qdd_pre;
    const int tl = tid >> 5, j = tid & 31;
    const long long bt = (long long)b * TT + t0 + tl;
#pragma unroll
    for (int ee = 0; ee < 8; ++ee) {
      int e = ee * 32 + j;
      int n = e & 15, m = e >> 4;
      float val = W[e]
                + QW1[bt * 32 + 2 * m] * QW2[bt * 32 + 2 * n]
                + QW1[bt * 32 + 2 * m + 1] * QW2[bt * 32 + 2 * n + 1];
      if (m == n) val += QDD[bt * 16 + n];
      sH[tl * 256 + ((m >> 2) * 16 + n) * 4 + (m & 3)] = f2bf(val);
    }
    __syncthreads();
#pragma unroll
    for (int kk = 0; kk < 4; ++kk) {
      int idx = tid + kk * 256;
      int tl2 = idx >> 7, off = idx & 127;
      mqA[(((long long)(pass * 2 + b) * TT + t0 + tl2)) * 128 + off] =
          (uint)sH[tl2 * 256 + 2 * off] | ((uint)sH[tl2 * 256 + 2 * off + 1] << 16);
    }
  } else {
    // ---- kw pack -> kwsT2[(pass*2+b)*40 + j2][s] u32 pairs (pitch 1024) ----
    float (*sKW)[84] = (float (*)[84])sPool;
    const int bidx = g - 2048;                 // 64
    const int sch = bidx & 15, b = (bidx >> 4) & 1, pass = bidx >> 5;
    const int s0b = sch * 64;
    const float* KW1 = pass ? kw1_post : kw1_pre;
    const float* KW2 = pass ? kw2_post : kw2_pre;
    const float* KDD = pass ? kdd_post : kdd_pre;
#pragma unroll
    for (int k2 = 0; k2 < 5; ++k2) {
      int idx = tid + k2 * 256;
      int s = idx / 20, q4 = idx % 20;
      long long bs = (long long)b * TT + s0b + s;
      float4 vv; int dst;
      if (q4 < 8)       { vv = ((const float4*)(KW1 + bs * 32))[q4];      dst = q4 * 4; }
      else if (q4 < 16) { vv = ((const float4*)(KW2 + bs * 32))[q4 - 8];  dst = 32 + (q4 - 8) * 4; }
      else              { vv = ((const float4*)(KDD + bs * 16))[q4 - 16]; dst = 64 + (q4 - 16) * 4; }
      *(float4*)(&sKW[s][dst]) = vv;
    }
    __syncthreads();
#pragma unroll
    for (int k2 = 0; k2 < 10; ++k2) {
      int idx = tid + k2 * 256;
      int j2 = idx >> 6, s = idx & 63;
      uint pr = (uint)f2bf(sKW[s][2 * j2]) | ((uint)f2bf(sKW[s][2 * j2 + 1]) << 16);
      kwsT2[((long long)(pass * 2 + b) * 40 + j2) * 1024 + s0b + s] = pr;
    }
  }
}

// ---------- KB: MFMA-proj + softmax; wave = (t, half-band) ----------
__global__ __launch_bounds__(512, 2)
void kb_proj(const uint* __restrict__ mqA, const uint* __restrict__ kwsT2,
             ushort* __restrict__ S)
{
  const int tid = threadIdx.x;
  const int raw = blockIdx.x;                  // 512 = 8*64
  const int job = (raw & 7) * 64 + (raw >> 3);
  const int b = job >> 8, tq = job & 255;
  const int t0 = tq * 4;
  const int t32 = t0 & ~31;
  const int s0 = (t32 >= WIN) ? t32 - WIN : 0;
  const int lane = tid & 63, wv = tid >> 6;
  const int t = t0 + (wv & 3);
  const int half = wv >> 2;                    // 0: cols 0-143, 1: cols 144-287
  const int q = lane >> 4, cl = lane & 15;
  const int n0 = 4 * q;

  __shared__ uint skw[40][292];
  __shared__ float sZp[8][4][4];               // [wave][quad-group][j]

  s16x8 aPre, aPost;
  {
    uint2 a1 = *(const uint2*)(mqA + (((long long)b * TT + t) * 128) + lane * 2);
    uint2 a2 = *(const uint2*)(mqA + (((long long)(2 + b) * TT + t) * 128) + lane * 2);
    union { uint u[4]; s16x8 v; } pk;
    pk.u[0] = a1.x; pk.u[1] = a1.y; pk.u[2] = 0; pk.u[3] = 0; aPre = pk.v;
    pk.u[0] = a2.x; pk.u[1] = a2.y; aPost = pk.v;
  }

  const uint* kwb1 = kwsT2 + (long long)b * (40 * 1024);
  const uint* kwb2 = kwsT2 + (long long)(2 + b) * (40 * 1024);
#define STAGE(BASE)                                                          \
  { _Pragma("unroll") for (int i = 0; i < 6; ++i) {                          \
      int idx = tid + i * 512;                                               \
      if (idx < 2880) {                                                      \
        int j2 = idx / 72, s4 = idx % 72;                                    \
        uint4 vv = *(const uint4*)((BASE) + (long long)j2 * 1024 + s0 + s4 * 4); \
        *(uint4*)(&skw[j2][s4 * 4]) = vv; } } }

  STAGE(kwb1);
  __syncthreads();

  ushort* Sbt = S + (((long long)(b * TT + t)) * NH) * SW;
  uint usv[9][2];
  float zp[4] = {0.f, 0.f, 0.f, 0.f};

  // ================= PASS 1 =================
#pragma unroll
  for (int i = 0; i < 9; ++i) {
    const int gg = half * 9 + i;
    const int c = gg * 16 + cl;
    const int sg = s0 + c;
    ushort u0 = Sbt[(n0 + 0) * SW + c];
    ushort u1 = Sbt[(n0 + 1) * SW + c];
    ushort u2 = Sbt[(n0 + 2) * SW + c];
    ushort u3 = Sbt[(n0 + 3) * SW + c];
    union { uint u[4]; s16x8 v; } bf;
    bf.u[0] = (uint)u0 | ((uint)u1 << 16);
    bf.u[1] = (uint)u2 | ((uint)u3 << 16);
    bf.u[2] = 0; bf.u[3] = 0;
    f32x4 acc = {0.f, 0.f, 0.f, 0.f};
    acc = __builtin_amdgcn_mfma_f32_16x16x32_bf16(aPre, bf.v, acc, 0, 0, 0);
    float f0 = bf2f(u0), f1 = bf2f(u1), f2 = bf2f(u2), f3 = bf2f(u3);
    uint w0 = skw[n0 + 0][c], w1 = skw[n0 + 1][c], w2 = skw[n0 + 2][c], w3 = skw[n0 + 3][c];
    float hk0 = f0 * bflo(w0) + f1 * bflo(w1) + f2 * bflo(w2) + f3 * bflo(w3);
    float hk1 = f0 * bfhi(w0) + f1 * bfhi(w1) + f2 * bfhi(w2) + f3 * bfhi(w3);
    hk0 += __shfl_xor(hk0, 16); hk0 += __shfl_xor(hk0, 32);
    hk1 += __shfl_xor(hk1, 16); hk1 += __shfl_xor(hk1, 32);
    const bool valid = (sg <= t) && (sg + WIN > t);
    uint k20 = skw[16 + n0 + 0][c], k21 = skw[16 + n0 + 1][c];
    uint k22 = skw[16 + n0 + 2][c], k23 = skw[16 + n0 + 3][c];
    uint kd0 = skw[32 + 2 * q][c], kd1 = skw[32 + 2 * q + 1][c];
    float x0 = acc[0] + f0 + hk0 * bflo(k20) + hk1 * bfhi(k20) + f0 * bflo(kd0);
    float x1 = acc[1] + f1 + hk0 * bflo(k21) + hk1 * bfhi(k21) + f1 * bfhi(kd0);
    float x2 = acc[2] + f2 + hk0 * bflo(k22) + hk1 * bfhi(k22) + f2 * bflo(kd1);
    float x3 = acc[3] + f3 + hk0 * bflo(k23) + hk1 * bfhi(k23) + f3 * bfhi(kd1);
    float e0 = valid ? __expf(x0) : 0.f;
    float e1 = valid ? __expf(x1) : 0.f;
    float e2 = valid ? __expf(x2) : 0.f;
    float e3 = valid ? __expf(x3) : 0.f;
    zp[0] += e0; zp[1] += e1; zp[2] += e2; zp[3] += e3;
    usv[i][0] = (uint)f2bf(e0) | ((uint)f2bf(e1) << 16);
    usv[i][1] = (uint)f2bf(e2) | ((uint)f2bf(e3) << 16);
  }

  // ---- Z reduce per quad-group; combine half-band wave pair ----
#pragma unroll
  for (int j = 0; j < 4; ++j) {
    float z = zp[j];
    z += __shfl_xor(z, 1); z += __shfl_xor(z, 2);
    z += __shfl_xor(z, 4); z += __shfl_xor(z, 8);
    zp[j] = z;
  }
  if (cl == 0) {
#pragma unroll
    for (int j = 0; j < 4; ++j) sZp[wv][q][j] = zp[j];
  }
  __syncthreads();
  float rz[4];
#pragma unroll
  for (int j = 0; j < 4; ++j)
    rz[j] = 1.0f / (sZp[wv][q][j] + sZp[wv ^ 4][q][j]);
  STAGE(kwb2);
  __syncthreads();

  // ================= PASS 2 =================
#pragma unroll
  for (int i = 0; i < 9; ++i) {
    const int gg = half * 9 + i;
    const int c = gg * 16 + cl;
    float p0 = bflo(usv[i][0]) * rz[0];
    float p1 = bfhi(usv[i][0]) * rz[1];
    float p2 = bflo(usv[i][1]) * rz[2];
    float p3 = bfhi(usv[i][1]) * rz[3];
    union { uint u[4]; s16x8 v; } bf;
    bf.u[0] = (uint)f2bf(p0) | ((uint)f2bf(p1) << 16);
    bf.u[1] = (uint)f2bf(p2) | ((uint)f2bf(p3) << 16);
    bf.u[2] = 0; bf.u[3] = 0;
    f32x4 acc = {0.f, 0.f, 0.f, 0.f};
    acc = __builtin_amdgcn_mfma_f32_16x16x32_bf16(aPost, bf.v, acc, 0, 0, 0);
    uint w0 = skw[n0 + 0][c], w1 = skw[n0 + 1][c], w2 = skw[n0 + 2][c], w3 = skw[n0 + 3][c];
    float hk0 = p0 * bflo(w0) + p1 * bflo(w1) + p2 * bflo(w2) + p3 * bflo(w3);
    float hk1 = p0 * bfhi(w0) + p1 * bfhi(w1) + p2 * bfhi(w2) + p3 * bfhi(w3);
    hk0 += __shfl_xor(hk0, 16); hk0 += __shfl_xor(hk0, 32);
    hk1 += __shfl_xor(hk1, 16); hk1 += __shfl_xor(hk1, 32);
    uint k20 = skw[16 + n0 + 0][c], k21 = skw[16 + n0 + 1][c];
    uint k22 = skw[16 + n0 + 2][c], k23 = skw[16 + n0 + 3][c];
    uint kd0 = skw[32 + 2 * q][c], kd1 = skw[32 + 2 * q + 1][c];
    float x0 = acc[0] + p0 + hk0 * bflo(k20) + hk1 * bfhi(k20) + p0 * bflo(kd0);
    float x1 = acc[1] + p1 + hk0 * bflo(k21) + hk1 * bfhi(k21) + p1 * bfhi(kd0);
    float x2 = acc[2] + p2 + hk0 * bflo(k22) + hk1 * bfhi(k22) + p2 * bflo(kd1);
    float x3 = acc[3] + p3 + hk0 * bflo(k23) + hk1 * bfhi(k23) + p3 * bfhi(kd1);
    Sbt[(n0 + 0) * SW + c] = f2bf(x0);
    Sbt[(n0 + 1) * SW + c] = f2bf(x1);
    Sbt[(n0 + 2) * SW + c] = f2bf(x2);
    Sbt[(n0 + 3) * SW + c] = f2bf(x3);
  }
}

// ---------- KC: PV band GEMM per (b,h,32-t tile) ----------
__global__ __launch_bounds__(256, 4)
void kc_pv(const ushort* __restrict__ S, const ushort* __restrict__ v8,
           float* __restrict__ out)
{
  const int tid = threadIdx.x;
  const int raw = blockIdx.x;                  // 1024 = 8*128
  const int job = (raw & 7) * 128 + (raw >> 3);
  const int b = job >> 9, h = (job >> 5) & 15, tt = job & 31;
  const int t0 = tt * 32;
  const int s0 = (t0 >= WIN) ? t0 - WIN : 0;
  const int lane = tid & 63, wv = tid >> 6;

  __shared__ ushort sPt[32 * 296];

#pragma unroll
  for (int it = 0; it < 5; ++it) {
    int idx = tid + it * 256;
    if (idx < 32 * 36) {
      int r = idx / 36, sg = idx % 36;
      uint4 v = *(const uint4*)(S + (((long long)(b * TT + t0 + r)) * NH + h) * SW + sg * 8);
      *(uint4*)(&sPt[r * 296 + sg * 8]) = v;
    }
  }
  __syncthreads();

  const ushort* vbase = v8 + ((long long)(b * NH + h)) * (128 * DD * 8)
                           + ((long long)(s0 >> 3)) * (DD * 8);
  const int dcol = lane & 15, soct = lane >> 4;
  const int dt0 = wv * 2;
  f32x4 acc[2][2];
#pragma unroll
  for (int rt = 0; rt < 2; ++rt)
#pragma unroll
    for (int dd = 0; dd < 2; ++dd) acc[rt][dd] = (f32x4){0.f, 0.f, 0.f, 0.f};

#pragma unroll
  for (int ks = 0; ks < 9; ++ks) {
    s16x8 a0 = *(const s16x8*)(&sPt[(dcol) * 296 + ks * 32 + soct * 8]);
    s16x8 a1 = *(const s16x8*)(&sPt[(16 + dcol) * 296 + ks * 32 + soct * 8]);
#pragma unroll
    for (int dd = 0; dd < 2; ++dd) {
      s16x8 vb = *(const s16x8*)(vbase + (((long long)(ks * 4 + soct)) * DD + (dt0 + dd) * 16 + dcol) * 8);
      acc[0][dd] = __builtin_amdgcn_mfma_f32_16x16x32_bf16(a0, vb, acc[0][dd], 0, 0, 0);
      acc[1][dd] = __builtin_amdgcn_mfma_f32_16x16x32_bf16(a1, vb, acc[1][dd], 0, 0, 0);
    }
  }
  const int r0 = (lane >> 4) * 4;
#pragma unroll
  for (int rt = 0; rt < 2; ++rt)
#pragma unroll
    for (int dd = 0; dd < 2; ++dd)
#pragma unroll
      for (int j = 0; j < 4; ++j) {
        int trow = t0 + rt * 16 + r0 + j;
        out[(((long long)(b * TT + trow)) * NH + h) * DD + (dt0 + dd) * 16 + dcol] = acc[rt][dd][j];
      }
}

extern "C" void kernel_launch(void* const* d_in, const int* in_sizes, int n_in,
                              void* d_out, int out_size, void* d_ws, size_t ws_size,
                              hipStream_t stream) {
  const float* q        = (const float*)d_in[0];
  const float* k        = (const float*)d_in[1];
  const float* v        = (const float*)d_in[2];
  const float* w_pre    = (const float*)d_in[3];
  const float* w_post   = (const float*)d_in[4];
  const float* qw1_pre  = (const float*)d_in[5];
  const float* qw2_pre  = (const float*)d_in[6];
  const float* kw1_pre  = (const float*)d_in[7];
  const float* kw2_pre  = (const float*)d_in[8];
  const float* qw1_post = (const float*)d_in[9];
  const float* qw2_post = (const float*)d_in[10];
  const float* kw1_post = (const float*)d_in[11];
  const float* kw2_post = (const float*)d_in[12];
  const float* qdd_pre  = (const float*)d_in[13];
  const float* kdd_pre  = (const float*)d_in[14];
  const float* qdd_post = (const float*)d_in[15];
  const float* kdd_post = (const float*)d_in[16];
  float* out = (float*)d_out;

  // ws: v8 8M | S 18.9M | mqA 2M | kwsT2 640K  (~29.5 MB)
  ushort* v8    = (ushort*)d_ws;
  ushort* S     = (ushort*)((char*)d_ws + 8388608ll);
  uint*   mqA   = (uint*)  ((char*)d_ws + 27262976ll);
  uint*   kwsT2 = (uint*)  ((char*)d_ws + 29360128ll);

  ka_qk<<<2112, 256, 0, stream>>>(q, k, v,
                                  w_pre, w_post,
                                  qw1_pre, qw2_pre, qdd_pre, kw1_pre, kw2_pre, kdd_pre,
                                  qw1_post, qw2_post, qdd_post, kw1_post, kw2_post, kdd_post,
                                  S, v8, mqA, kwsT2);
  kb_proj<<<512, 512, 0, stream>>>(mqA, kwsT2, S);
  kc_pv  <<<1024, 256, 0, stream>>>(S, v8, out);
}

// Round 17
// 55.676 us; speedup vs baseline: 1.2442x; 1.2442x over previous
//
#include <hip/hip_runtime.h>

#define TT 1024
#define NH 16
#define DD 128
#define WIN 256
#define SW 288            // stored band width (18 x 16); S layout: [b][t][h][SW]
#define SCALE 0.08838834764831845f

typedef float f32x4 __attribute__((ext_vector_type(4)));
typedef short s16x8 __attribute__((ext_vector_type(8)));

__device__ __forceinline__ ushort f2bf(float x) {
  union { float f; unsigned u; } v; v.f = x;
  unsigned r = v.u + 0x7FFFu + ((v.u >> 16) & 1u);
  return (ushort)(r >> 16);
}
__device__ __forceinline__ float bf2f(ushort u) {
  union { unsigned u; float f; } v; v.u = ((unsigned)u) << 16; return v.f;
}
__device__ __forceinline__ float bflo(uint p) {
  union { unsigned u; float f; } v; v.u = p << 16; return v.f;
}
__device__ __forceinline__ float bfhi(uint p) {
  union { unsigned u; float f; } v; v.u = p & 0xFFFF0000u; return v.f;
}

// ---------- prep1: k -> bf16 [b][h][doct16][t][8] (k only; q converted in ka) ----------
__global__ __launch_bounds__(256)
void prep1(const float* __restrict__ k, ushort* __restrict__ kb8)
{
  const int g = blockIdx.x;                    // 512
  const int tid = threadIdx.x;
  __shared__ float sPool[64 * 132];
  const int tt = g & 15, h = (g >> 4) & 15, b = g >> 8;
  const int t0 = tt * 64;
#pragma unroll
  for (int it = 0; it < 8; ++it) {
    int idx = tid + it * 256;
    int r = idx >> 5, cg = idx & 31;
    float4 x = *(const float4*)(k + (((long long)(b * TT + t0 + r)) * NH + h) * DD + cg * 4);
    *(float4*)(&sPool[r * 132 + cg * 4]) = x;
  }
  __syncthreads();
#pragma unroll
  for (int it = 0; it < 4; ++it) {
    int idx = tid + it * 256;
    int t = idx & 63, doct = idx >> 6;
    union { ushort u[8]; uint4 v; } pk;
#pragma unroll
    for (int e = 0; e < 8; ++e)
      pk.u[e] = f2bf(sPool[t * 132 + doct * 8 + e]);
    *(uint4*)(kb8 + ((((long long)(b * NH + h)) * 16 + doct) * TT + t0 + t) * 8) = pk.v;
  }
}

// ---------- KA+: 1024 QK jobs | 512 v8 | 512 mqA | 64 kw (prep overlapped) ----------
__global__ __launch_bounds__(256, 4)
void ka_qk(const float* __restrict__ q, const ushort* __restrict__ kb8,
           const float* __restrict__ v,
           const float* __restrict__ w_pre, const float* __restrict__ w_post,
           const float* __restrict__ qw1_pre, const float* __restrict__ qw2_pre,
           const float* __restrict__ qdd_pre,
           const float* __restrict__ kw1_pre, const float* __restrict__ kw2_pre,
           const float* __restrict__ kdd_pre,
           const float* __restrict__ qw1_post, const float* __restrict__ qw2_post,
           const float* __restrict__ qdd_post,
           const float* __restrict__ kw1_post, const float* __restrict__ kw2_post,
           const float* __restrict__ kdd_post,
           ushort* __restrict__ S, ushort* __restrict__ v8,
           uint* __restrict__ mqA, uint* __restrict__ kwsT2)
{
  const int g = blockIdx.x;                    // 2112
  const int tid = threadIdx.x;
  __shared__ float sPool[64 * 132];            // 33.8 KB shared by all branches

  if (g < 1024) {
    // ---- QK band GEMM per (b,h,32-t tile) -> S[b][t][h][*] bf16 ----
    float* strip = sPool;                      // 16*300 floats (19.2 KB)
    const int job = (g & 7) * 128 + (g >> 3);  // XCD swizzle
    const int b = job >> 9, h = (job >> 5) & 15, tt = job & 31;
    const int t0 = tt * 32;
    const int s0 = (t0 >= WIN) ? t0 - WIN : 0;
    const int lane = tid & 63, wv = tid >> 6;

    // stage this block's 32 q rows (fp32, coalesced) and build fragments w/ SCALE
    {
      const float* qsrc = q + (((long long)(b * TT + t0)) * NH + h) * DD;
#pragma unroll
      for (int it = 0; it < 4; ++it) {
        int idx = tid + it * 256;              // 1024 float4 = 32 rows x 32
        int r = idx >> 5, cg = idx & 31;
        float4 x = *(const float4*)(qsrc + (long long)r * (NH * DD) + cg * 4);
        *(float4*)(&sPool[r * 132 + cg * 4]) = x;
      }
    }
    __syncthreads();
    s16x8 qa[2][4];
    {
      const int ko = lane >> 4;
#pragma unroll
      for (int rt2 = 0; rt2 < 2; ++rt2) {
        int rloc = rt2 * 16 + (lane & 15);
#pragma unroll
        for (int kk = 0; kk < 4; ++kk) {
          union { ushort u[8]; s16x8 v; } pk;
#pragma unroll
          for (int e = 0; e < 8; ++e)
            pk.u[e] = f2bf(sPool[rloc * 132 + kk * 32 + ko * 8 + e] * SCALE);
          qa[rt2][kk] = pk.v;
        }
      }
    }
    __syncthreads();                           // sPool now free for strip

    const ushort* kbase = kb8 + ((long long)(b * NH + h)) * 16 * (TT * 8);

    for (int rt = 0; rt < 2; ++rt) {
      const int tlo = t0 + rt * 16;
      int cl0 = tlo - (WIN - 1) - s0; if (cl0 < 0) cl0 = 0;
      const int chi = tlo + 15 - s0;
      const int stb = cl0 >> 4;
      const int nst = (chi >> 4) - stb + 1;
      for (int sti = wv; sti < nst; sti += 4) {
        const int cst = (stb + sti) * 16;
        const int scol = s0 + cst + (lane & 15);
        const int ko = lane >> 4;
        f32x4 acc = {0.f, 0.f, 0.f, 0.f};
#pragma unroll
        for (int kk = 0; kk < 4; ++kk) {
          s16x8 kb = *(const s16x8*)(kbase + ((long long)(kk * 4 + ko)) * (TT * 8) + scol * 8);
          acc = __builtin_amdgcn_mfma_f32_16x16x32_bf16(qa[rt][kk], kb, acc, 0, 0, 0);
        }
        const int r0 = (lane >> 4) * 4;
#pragma unroll
        for (int j = 0; j < 4; ++j)
          strip[(r0 + j) * 300 + cst + (lane & 15)] = acc[j];
      }
      __syncthreads();
#pragma unroll
      for (int it = 0; it < 3; ++it) {
        int idx = tid + it * 256;
        if (idx < 16 * 36) {
          int r = idx / 36, sg = idx % 36;
          union { ushort u[8]; uint4 v; } pk;
#pragma unroll
          for (int e = 0; e < 8; ++e)
            pk.u[e] = f2bf(strip[r * 300 + sg * 8 + e]);
          *(uint4*)(S + (((long long)(b * TT + tlo + r)) * NH + h) * SW + sg * 8) = pk.v;
        }
      }
      __syncthreads();
    }
  } else if (g < 1536) {
    // ---- v fp32 -> v8 bf16 [b][h][soct128][d][8] ----
    const int bidx = g - 1024;
    const int st = bidx & 15, h = (bidx >> 4) & 15, b = bidx >> 8;
    const int s0 = st * 64;
#pragma unroll
    for (int it = 0; it < 8; ++it) {
      int idx = tid + it * 256;
      int r = idx >> 5, cg = idx & 31;
      float4 x = *(const float4*)(v + (((long long)(b * TT + s0 + r)) * NH + h) * DD + cg * 4);
      *(float4*)(&sPool[r * 132 + cg * 4]) = x;
    }
    __syncthreads();
#pragma unroll
    for (int it = 0; it < 4; ++it) {
      int idx = tid + it * 256;
      int d = idx & 127, so = idx >> 7;
      union { ushort u[8]; uint4 v; } pk;
#pragma unroll
      for (int e = 0; e < 8; ++e)
        pk.u[e] = f2bf(sPool[(so * 8 + e) * 132 + d]);
      *(uint4*)(v8 + ((((long long)(b * NH + h)) * 128 + st * 8 + so) * DD + d) * 8) = pk.v;
    }
  } else if (g < 2048) {
    // ---- mqA: (pass,b) x 8 t's. Mq_rest = W + qw1*qw2^T + diag(qdd) ----
    ushort* sH = (ushort*)sPool;               // [8][256]
    const int gg = g - 1536;
    const int tgrp = gg & 127, b = (gg >> 7) & 1, pass = gg >> 8;
    const int t0 = tgrp * 8;
    const float* W   = pass ? w_post   : w_pre;
    const float* QW1 = pass ? qw1_post : qw1_pre;
    const float* QW2 = pass ? qw2_post : qw2_pre;
    const float* QDD = pass ? qdd_post : qdd_pre;
    const int tl = tid >> 5, j = tid & 31;
    const long long bt = (long long)b * TT + t0 + tl;
#pragma unroll
    for (int ee = 0; ee < 8; ++ee) {
      int e = ee * 32 + j;
      int n = e & 15, m = e >> 4;
      float val = W[e]
                + QW1[bt * 32 + 2 * m] * QW2[bt * 32 + 2 * n]
                + QW1[bt * 32 + 2 * m + 1] * QW2[bt * 32 + 2 * n + 1];
      if (m == n) val += QDD[bt * 16 + n];
      sH[tl * 256 + ((m >> 2) * 16 + n) * 4 + (m & 3)] = f2bf(val);
    }
    __syncthreads();
#pragma unroll
    for (int kk = 0; kk < 4; ++kk) {
      int idx = tid + kk * 256;
      int tl2 = idx >> 7, off = idx & 127;
      mqA[(((long long)(pass * 2 + b) * TT + t0 + tl2)) * 128 + off] =
          (uint)sH[tl2 * 256 + 2 * off] | ((uint)sH[tl2 * 256 + 2 * off + 1] << 16);
    }
  } else {
    // ---- kw pack -> kwsT2[(pass*2+b)*40 + j2][s] u32 pairs (pitch 1024) ----
    float (*sKW)[84] = (float (*)[84])sPool;
    const int bidx = g - 2048;                 // 64
    const int sch = bidx & 15, b = (bidx >> 4) & 1, pass = bidx >> 5;
    const int s0b = sch * 64;
    const float* KW1 = pass ? kw1_post : kw1_pre;
    const float* KW2 = pass ? kw2_post : kw2_pre;
    const float* KDD = pass ? kdd_post : kdd_pre;
#pragma unroll
    for (int k2 = 0; k2 < 5; ++k2) {
      int idx = tid + k2 * 256;
      int s = idx / 20, q4 = idx % 20;
      long long bs = (long long)b * TT + s0b + s;
      float4 vv; int dst;
      if (q4 < 8)       { vv = ((const float4*)(KW1 + bs * 32))[q4];      dst = q4 * 4; }
      else if (q4 < 16) { vv = ((const float4*)(KW2 + bs * 32))[q4 - 8];  dst = 32 + (q4 - 8) * 4; }
      else              { vv = ((const float4*)(KDD + bs * 16))[q4 - 16]; dst = 64 + (q4 - 16) * 4; }
      *(float4*)(&sKW[s][dst]) = vv;
    }
    __syncthreads();
#pragma unroll
    for (int k2 = 0; k2 < 10; ++k2) {
      int idx = tid + k2 * 256;
      int j2 = idx >> 6, s = idx & 63;
      uint pr = (uint)f2bf(sKW[s][2 * j2]) | ((uint)f2bf(sKW[s][2 * j2 + 1]) << 16);
      kwsT2[((long long)(pass * 2 + b) * 40 + j2) * 1024 + s0b + s] = pr;
    }
  }
}

// ---------- KB: MFMA-proj + softmax; wave = (t, half-band) ----------
__global__ __launch_bounds__(512, 2)
void kb_proj(const uint* __restrict__ mqA, const uint* __restrict__ kwsT2,
             ushort* __restrict__ S)
{
  const int tid = threadIdx.x;
  const int raw = blockIdx.x;                  // 512 = 8*64
  const int job = (raw & 7) * 64 + (raw >> 3);
  const int b = job >> 8, tq = job & 255;
  const int t0 = tq * 4;
  const int t32 = t0 & ~31;
  const int s0 = (t32 >= WIN) ? t32 - WIN : 0;
  const int lane = tid & 63, wv = tid >> 6;
  const int t = t0 + (wv & 3);
  const int half = wv >> 2;                    // 0: cols 0-143, 1: cols 144-287
  const int q = lane >> 4, cl = lane & 15;
  const int n0 = 4 * q;

  __shared__ uint skw[40][292];
  __shared__ float sZp[8][4][4];               // [wave][quad-group][j]

  s16x8 aPre, aPost;
  {
    uint2 a1 = *(const uint2*)(mqA + (((long long)b * TT + t) * 128) + lane * 2);
    uint2 a2 = *(const uint2*)(mqA + (((long long)(2 + b) * TT + t) * 128) + lane * 2);
    union { uint u[4]; s16x8 v; } pk;
    pk.u[0] = a1.x; pk.u[1] = a1.y; pk.u[2] = 0; pk.u[3] = 0; aPre = pk.v;
    pk.u[0] = a2.x; pk.u[1] = a2.y; aPost = pk.v;
  }

  const uint* kwb1 = kwsT2 + (long long)b * (40 * 1024);
  const uint* kwb2 = kwsT2 + (long long)(2 + b) * (40 * 1024);
#define STAGE(BASE)                                                          \
  { _Pragma("unroll") for (int i = 0; i < 6; ++i) {                          \
      int idx = tid + i * 512;                                               \
      if (idx < 2880) {                                                      \
        int j2 = idx / 72, s4 = idx % 72;                                    \
        uint4 vv = *(const uint4*)((BASE) + (long long)j2 * 1024 + s0 + s4 * 4); \
        *(uint4*)(&skw[j2][s4 * 4]) = vv; } } }

  STAGE(kwb1);
  __syncthreads();

  ushort* Sbt = S + (((long long)(b * TT + t)) * NH) * SW;
  uint usv[9][2];
  float zp[4] = {0.f, 0.f, 0.f, 0.f};

  // ================= PASS 1 =================
#pragma unroll
  for (int i = 0; i < 9; ++i) {
    const int gg = half * 9 + i;
    const int c = gg * 16 + cl;
    const int sg = s0 + c;
    ushort u0 = Sbt[(n0 + 0) * SW + c];
    ushort u1 = Sbt[(n0 + 1) * SW + c];
    ushort u2 = Sbt[(n0 + 2) * SW + c];
    ushort u3 = Sbt[(n0 + 3) * SW + c];
    union { uint u[4]; s16x8 v; } bf;
    bf.u[0] = (uint)u0 | ((uint)u1 << 16);
    bf.u[1] = (uint)u2 | ((uint)u3 << 16);
    bf.u[2] = 0; bf.u[3] = 0;
    f32x4 acc = {0.f, 0.f, 0.f, 0.f};
    acc = __builtin_amdgcn_mfma_f32_16x16x32_bf16(aPre, bf.v, acc, 0, 0, 0);
    float f0 = bf2f(u0), f1 = bf2f(u1), f2 = bf2f(u2), f3 = bf2f(u3);
    uint w0 = skw[n0 + 0][c], w1 = skw[n0 + 1][c], w2 = skw[n0 + 2][c], w3 = skw[n0 + 3][c];
    float hk0 = f0 * bflo(w0) + f1 * bflo(w1) + f2 * bflo(w2) + f3 * bflo(w3);
    float hk1 = f0 * bfhi(w0) + f1 * bfhi(w1) + f2 * bfhi(w2) + f3 * bfhi(w3);
    hk0 += __shfl_xor(hk0, 16); hk0 += __shfl_xor(hk0, 32);
    hk1 += __shfl_xor(hk1, 16); hk1 += __shfl_xor(hk1, 32);
    const bool valid = (sg <= t) && (sg + WIN > t);
    uint k20 = skw[16 + n0 + 0][c], k21 = skw[16 + n0 + 1][c];
    uint k22 = skw[16 + n0 + 2][c], k23 = skw[16 + n0 + 3][c];
    uint kd0 = skw[32 + 2 * q][c], kd1 = skw[32 + 2 * q + 1][c];
    float x0 = acc[0] + f0 + hk0 * bflo(k20) + hk1 * bfhi(k20) + f0 * bflo(kd0);
    float x1 = acc[1] + f1 + hk0 * bflo(k21) + hk1 * bfhi(k21) + f1 * bfhi(kd0);
    float x2 = acc[2] + f2 + hk0 * bflo(k22) + hk1 * bfhi(k22) + f2 * bflo(kd1);
    float x3 = acc[3] + f3 + hk0 * bflo(k23) + hk1 * bfhi(k23) + f3 * bfhi(kd1);
    float e0 = valid ? __expf(x0) : 0.f;
    float e1 = valid ? __expf(x1) : 0.f;
    float e2 = valid ? __expf(x2) : 0.f;
    float e3 = valid ? __expf(x3) : 0.f;
    zp[0] += e0; zp[1] += e1; zp[2] += e2; zp[3] += e3;
    usv[i][0] = (uint)f2bf(e0) | ((uint)f2bf(e1) << 16);
    usv[i][1] = (uint)f2bf(e2) | ((uint)f2bf(e3) << 16);
  }

  // ---- Z reduce per quad-group; combine half-band wave pair ----
#pragma unroll
  for (int j = 0; j < 4; ++j) {
    float z = zp[j];
    z += __shfl_xor(z, 1); z += __shfl_xor(z, 2);
    z += __shfl_xor(z, 4); z += __shfl_xor(z, 8);
    zp[j] = z;
  }
  if (cl == 0) {
#pragma unroll
    for (int j = 0; j < 4; ++j) sZp[wv][q][j] = zp[j];
  }
  __syncthreads();
  float rz[4];
#pragma unroll
  for (int j = 0; j < 4; ++j)
    rz[j] = 1.0f / (sZp[wv][q][j] + sZp[wv ^ 4][q][j]);
  STAGE(kwb2);
  __syncthreads();

  // ================= PASS 2 =================
#pragma unroll
  for (int i = 0; i < 9; ++i) {
    const int gg = half * 9 + i;
    const int c = gg * 16 + cl;
    float p0 = bflo(usv[i][0]) * rz[0];
    float p1 = bfhi(usv[i][0]) * rz[1];
    float p2 = bflo(usv[i][1]) * rz[2];
    float p3 = bfhi(usv[i][1]) * rz[3];
    union { uint u[4]; s16x8 v; } bf;
    bf.u[0] = (uint)f2bf(p0) | ((uint)f2bf(p1) << 16);
    bf.u[1] = (uint)f2bf(p2) | ((uint)f2bf(p3) << 16);
    bf.u[2] = 0; bf.u[3] = 0;
    f32x4 acc = {0.f, 0.f, 0.f, 0.f};
    acc = __builtin_amdgcn_mfma_f32_16x16x32_bf16(aPost, bf.v, acc, 0, 0, 0);
    uint w0 = skw[n0 + 0][c], w1 = skw[n0 + 1][c], w2 = skw[n0 + 2][c], w3 = skw[n0 + 3][c];
    float hk0 = p0 * bflo(w0) + p1 * bflo(w1) + p2 * bflo(w2) + p3 * bflo(w3);
    float hk1 = p0 * bfhi(w0) + p1 * bfhi(w1) + p2 * bfhi(w2) + p3 * bfhi(w3);
    hk0 += __shfl_xor(hk0, 16); hk0 += __shfl_xor(hk0, 32);
    hk1 += __shfl_xor(hk1, 16); hk1 += __shfl_xor(hk1, 32);
    uint k20 = skw[16 + n0 + 0][c], k21 = skw[16 + n0 + 1][c];
    uint k22 = skw[16 + n0 + 2][c], k23 = skw[16 + n0 + 3][c];
    uint kd0 = skw[32 + 2 * q][c], kd1 = skw[32 + 2 * q + 1][c];
    float x0 = acc[0] + p0 + hk0 * bflo(k20) + hk1 * bfhi(k20) + p0 * bflo(kd0);
    float x1 = acc[1] + p1 + hk0 * bflo(k21) + hk1 * bfhi(k21) + p1 * bfhi(kd0);
    float x2 = acc[2] + p2 + hk0 * bflo(k22) + hk1 * bfhi(k22) + p2 * bflo(kd1);
    float x3 = acc[3] + p3 + hk0 * bflo(k23) + hk1 * bfhi(k23) + p3 * bfhi(kd1);
    Sbt[(n0 + 0) * SW + c] = f2bf(x0);
    Sbt[(n0 + 1) * SW + c] = f2bf(x1);
    Sbt[(n0 + 2) * SW + c] = f2bf(x2);
    Sbt[(n0 + 3) * SW + c] = f2bf(x3);
  }
}

// ---------- KC: PV band GEMM per (b,h,32-t tile) ----------
__global__ __launch_bounds__(256, 4)
void kc_pv(const ushort* __restrict__ S, const ushort* __restrict__ v8,
           float* __restrict__ out)
{
  const int tid = threadIdx.x;
  const int raw = blockIdx.x;                  // 1024 = 8*128
  const int job = (raw & 7) * 128 + (raw >> 3);
  const int b = job >> 9, h = (job >> 5) & 15, tt = job & 31;
  const int t0 = tt * 32;
  const int s0 = (t0 >= WIN) ? t0 - WIN : 0;
  const int lane = tid & 63, wv = tid >> 6;

  __shared__ ushort sPt[32 * 296];

#pragma unroll
  for (int it = 0; it < 5; ++it) {
    int idx = tid + it * 256;
    if (idx < 32 * 36) {
      int r = idx / 36, sg = idx % 36;
      uint4 v = *(const uint4*)(S + (((long long)(b * TT + t0 + r)) * NH + h) * SW + sg * 8);
      *(uint4*)(&sPt[r * 296 + sg * 8]) = v;
    }
  }
  __syncthreads();

  const ushort* vbase = v8 + ((long long)(b * NH + h)) * (128 * DD * 8)
                           + ((long long)(s0 >> 3)) * (DD * 8);
  const int dcol = lane & 15, soct = lane >> 4;
  const int dt0 = wv * 2;
  f32x4 acc[2][2];
#pragma unroll
  for (int rt = 0; rt < 2; ++rt)
#pragma unroll
    for (int dd = 0; dd < 2; ++dd) acc[rt][dd] = (f32x4){0.f, 0.f, 0.f, 0.f};

#pragma unroll
  for (int ks = 0; ks < 9; ++ks) {
    s16x8 a0 = *(const s16x8*)(&sPt[(dcol) * 296 + ks * 32 + soct * 8]);
    s16x8 a1 = *(const s16x8*)(&sPt[(16 + dcol) * 296 + ks * 32 + soct * 8]);
#pragma unroll
    for (int dd = 0; dd < 2; ++dd) {
      s16x8 vb = *(const s16x8*)(vbase + (((long long)(ks * 4 + soct)) * DD + (dt0 + dd) * 16 + dcol) * 8);
      acc[0][dd] = __builtin_amdgcn_mfma_f32_16x16x32_bf16(a0, vb, acc[0][dd], 0, 0, 0);
      acc[1][dd] = __builtin_amdgcn_mfma_f32_16x16x32_bf16(a1, vb, acc[1][dd], 0, 0, 0);
    }
  }
  const int r0 = (lane >> 4) * 4;
#pragma unroll
  for (int rt = 0; rt < 2; ++rt)
#pragma unroll
    for (int dd = 0; dd < 2; ++dd)
#pragma unroll
      for (int j = 0; j < 4; ++j) {
        int trow = t0 + rt * 16 + r0 + j;
        out[(((long long)(b * TT + trow)) * NH + h) * DD + (dt0 + dd) * 16 + dcol] = acc[rt][dd][j];
      }
}

extern "C" void kernel_launch(void* const* d_in, const int* in_sizes, int n_in,
                              void* d_out, int out_size, void* d_ws, size_t ws_size,
                              hipStream_t stream) {
  const float* q        = (const float*)d_in[0];
  const float* k        = (const float*)d_in[1];
  const float* v        = (const float*)d_in[2];
  const float* w_pre    = (const float*)d_in[3];
  const float* w_post   = (const float*)d_in[4];
  const float* qw1_pre  = (const float*)d_in[5];
  const float* qw2_pre  = (const float*)d_in[6];
  const float* kw1_pre  = (const float*)d_in[7];
  const float* kw2_pre  = (const float*)d_in[8];
  const float* qw1_post = (const float*)d_in[9];
  const float* qw2_post = (const float*)d_in[10];
  const float* kw1_post = (const float*)d_in[11];
  const float* kw2_post = (const float*)d_in[12];
  const float* qdd_pre  = (const float*)d_in[13];
  const float* kdd_pre  = (const float*)d_in[14];
  const float* qdd_post = (const float*)d_in[15];
  const float* kdd_post = (const float*)d_in[16];
  float* out = (float*)d_out;

  // ws: kb8 8M | v8 8M | S 18M | mqA 2M | kwsT2 640K  (~37.5 MB)
  ushort* kb8   = (ushort*)d_ws;
  ushort* v8    = (ushort*)((char*)d_ws + 8388608ll);
  ushort* S     = (ushort*)((char*)d_ws + 16777216ll);
  uint*   mqA   = (uint*)  ((char*)d_ws + 35651584ll);
  uint*   kwsT2 = (uint*)  ((char*)d_ws + 37748736ll);

  prep1<<<512, 256, 0, stream>>>(k, kb8);
  ka_qk<<<2112, 256, 0, stream>>>(q, kb8, v,
                                  w_pre, w_post,
                                  qw1_pre, qw2_pre, qdd_pre, kw1_pre, kw2_pre, kdd_pre,
                                  qw1_post, qw2_post, qdd_post, kw1_post, kw2_post, kdd_post,
                                  S, v8, mqA, kwsT2);
  kb_proj<<<512, 512, 0, stream>>>(mqA, kwsT2, S);
  kc_pv  <<<1024, 256, 0, stream>>>(S, v8, out);
}

// Round 18
// 55.284 us; speedup vs baseline: 1.2530x; 1.0071x over previous
//
#include <hip/hip_runtime.h>

#define TT 1024
#define NH 16
#define DD 128
#define WIN 256
#define SW 288            // stored band width (18 x 16); S layout: [b][t][h][SW]
#define SCALE 0.08838834764831845f

typedef float f32x4 __attribute__((ext_vector_type(4)));
typedef short s16x8 __attribute__((ext_vector_type(8)));

__device__ __forceinline__ ushort f2bf(float x) {
  union { float f; unsigned u; } v; v.f = x;
  unsigned r = v.u + 0x7FFFu + ((v.u >> 16) & 1u);
  return (ushort)(r >> 16);
}
__device__ __forceinline__ float bf2f(ushort u) {
  union { unsigned u; float f; } v; v.u = ((unsigned)u) << 16; return v.f;
}
__device__ __forceinline__ float bflo(uint p) {
  union { unsigned u; float f; } v; v.u = p << 16; return v.f;
}
__device__ __forceinline__ float bfhi(uint p) {
  union { unsigned u; float f; } v; v.u = p & 0xFFFF0000u; return v.f;
}

// ---------- prep1: k -> bf16 [b][h][doct16][t][8] ----------
__global__ __launch_bounds__(256)
void prep1(const float* __restrict__ k, ushort* __restrict__ kb8)
{
  const int g = blockIdx.x;                    // 512
  const int tid = threadIdx.x;
  __shared__ float sPool[64 * 132];
  const int tt = g & 15, h = (g >> 4) & 15, b = g >> 8;
  const int t0 = tt * 64;
#pragma unroll
  for (int it = 0; it < 8; ++it) {
    int idx = tid + it * 256;
    int r = idx >> 5, cg = idx & 31;
    float4 x = *(const float4*)(k + (((long long)(b * TT + t0 + r)) * NH + h) * DD + cg * 4);
    *(float4*)(&sPool[r * 132 + cg * 4]) = x;
  }
  __syncthreads();
#pragma unroll
  for (int it = 0; it < 4; ++it) {
    int idx = tid + it * 256;
    int t = idx & 63, doct = idx >> 6;
    union { ushort u[8]; uint4 v; } pk;
#pragma unroll
    for (int e = 0; e < 8; ++e)
      pk.u[e] = f2bf(sPool[t * 132 + doct * 8 + e]);
    *(uint4*)(kb8 + ((((long long)(b * NH + h)) * 16 + doct) * TT + t0 + t) * 8) = pk.v;
  }
}

// ---------- KA+: 2048 QK jobs (16-t each) | 512 v8 | 512 mqA | 64 kw ----------
__global__ __launch_bounds__(256, 4)
void ka_qk(const float* __restrict__ q, const ushort* __restrict__ kb8,
           const float* __restrict__ v,
           const float* __restrict__ w_pre, const float* __restrict__ w_post,
           const float* __restrict__ qw1_pre, const float* __restrict__ qw2_pre,
           const float* __restrict__ qdd_pre,
           const float* __restrict__ kw1_pre, const float* __restrict__ kw2_pre,
           const float* __restrict__ kdd_pre,
           const float* __restrict__ qw1_post, const float* __restrict__ qw2_post,
           const float* __restrict__ qdd_post,
           const float* __restrict__ kw1_post, const float* __restrict__ kw2_post,
           const float* __restrict__ kdd_post,
           ushort* __restrict__ S, ushort* __restrict__ v8,
           uint* __restrict__ mqA, uint* __restrict__ kwsT2)
{
  const int g = blockIdx.x;                    // 3136
  const int tid = threadIdx.x;
  __shared__ float sPool[64 * 132];            // 33.8 KB shared by all branches

  if (g < 2048) {
    // ---- QK band GEMM per (b,h,16-t tile) -> S[b][t][h][*] bf16 ----
    float* strip = sPool;                      // 16*300 floats (19.2 KB)
    const int job = (g & 7) * 256 + (g >> 3);  // XCD swizzle
    const int b = job >> 10, h = (job >> 6) & 15, tt = job & 63;
    const int tlo = tt * 16;
    const int t32 = tlo & ~31;                 // S band base pinned to 32-t tile
    const int s0 = (t32 >= WIN) ? t32 - WIN : 0;
    const int lane = tid & 63, wv = tid >> 6;

    // stage this block's 16 q rows (fp32, coalesced), build fragments w/ SCALE
    {
      const float* qsrc = q + (((long long)(b * TT + tlo)) * NH + h) * DD;
#pragma unroll
      for (int it = 0; it < 2; ++it) {
        int idx = tid + it * 256;              // 512 float4 = 16 rows x 32
        int r = idx >> 5, cg = idx & 31;
        float4 x = *(const float4*)(qsrc + (long long)r * (NH * DD) + cg * 4);
        *(float4*)(&sPool[r * 132 + cg * 4]) = x;
      }
    }
    __syncthreads();
    s16x8 qa[4];
    {
      const int ko = lane >> 4;
      const int rloc = lane & 15;
#pragma unroll
      for (int kk = 0; kk < 4; ++kk) {
        union { ushort u[8]; s16x8 v; } pk;
#pragma unroll
        for (int e = 0; e < 8; ++e)
          pk.u[e] = f2bf(sPool[rloc * 132 + kk * 32 + ko * 8 + e] * SCALE);
        qa[kk] = pk.v;
      }
    }
    __syncthreads();                           // sPool now free for strip

    const ushort* kbase = kb8 + ((long long)(b * NH + h)) * 16 * (TT * 8);

    int cl0 = tlo - (WIN - 1) - s0; if (cl0 < 0) cl0 = 0;
    const int chi = tlo + 15 - s0;
    const int stb = cl0 >> 4;
    const int nst = (chi >> 4) - stb + 1;
    for (int sti = wv; sti < nst; sti += 4) {
      const int cst = (stb + sti) * 16;
      const int scol = s0 + cst + (lane & 15);
      const int ko = lane >> 4;
      f32x4 acc = {0.f, 0.f, 0.f, 0.f};
#pragma unroll
      for (int kk = 0; kk < 4; ++kk) {
        s16x8 kb = *(const s16x8*)(kbase + ((long long)(kk * 4 + ko)) * (TT * 8) + scol * 8);
        acc = __builtin_amdgcn_mfma_f32_16x16x32_bf16(qa[kk], kb, acc, 0, 0, 0);
      }
      const int r0 = (lane >> 4) * 4;
#pragma unroll
      for (int j = 0; j < 4; ++j)
        strip[(r0 + j) * 300 + cst + (lane & 15)] = acc[j];
    }
    __syncthreads();
#pragma unroll
    for (int it = 0; it < 3; ++it) {
      int idx = tid + it * 256;
      if (idx < 16 * 36) {
        int r = idx / 36, sg = idx % 36;
        union { ushort u[8]; uint4 v; } pk;
#pragma unroll
        for (int e = 0; e < 8; ++e)
          pk.u[e] = f2bf(strip[r * 300 + sg * 8 + e]);
        *(uint4*)(S + (((long long)(b * TT + tlo + r)) * NH + h) * SW + sg * 8) = pk.v;
      }
    }
  } else if (g < 2560) {
    // ---- v fp32 -> v8 bf16 [b][h][soct128][d][8] ----
    const int bidx = g - 2048;
    const int st = bidx & 15, h = (bidx >> 4) & 15, b = bidx >> 8;
    const int s0 = st * 64;
#pragma unroll
    for (int it = 0; it < 8; ++it) {
      int idx = tid + it * 256;
      int r = idx >> 5, cg = idx & 31;
      float4 x = *(const float4*)(v + (((long long)(b * TT + s0 + r)) * NH + h) * DD + cg * 4);
      *(float4*)(&sPool[r * 132 + cg * 4]) = x;
    }
    __syncthreads();
#pragma unroll
    for (int it = 0; it < 4; ++it) {
      int idx = tid + it * 256;
      int d = idx & 127, so = idx >> 7;
      union { ushort u[8]; uint4 v; } pk;
#pragma unroll
      for (int e = 0; e < 8; ++e)
        pk.u[e] = f2bf(sPool[(so * 8 + e) * 132 + d]);
      *(uint4*)(v8 + ((((long long)(b * NH + h)) * 128 + st * 8 + so) * DD + d) * 8) = pk.v;
    }
  } else if (g < 3072) {
    // ---- mqA: (pass,b) x 8 t's. Mq_rest = W + qw1*qw2^T + diag(qdd) ----
    ushort* sH = (ushort*)sPool;               // [8][256]
    const int gg = g - 2560;
    const int tgrp = gg & 127, b = (gg >> 7) & 1, pass = gg >> 8;
    const int t0 = tgrp * 8;
    const float* W   = pass ? w_post   : w_pre;
    const float* QW1 = pass ? qw1_post : qw1_pre;
    const float* QW2 = pass ? qw2_post : qw2_pre;
    const float* QDD = pass ? qdd_post : qdd_pre;
    const int tl = tid >> 5, j = tid & 31;
    const long long bt = (long long)b * TT + t0 + tl;
#pragma unroll
    for (int ee = 0; ee < 8; ++ee) {
      int e = ee * 32 + j;
      int n = e & 15, m = e >> 4;
      float val = W[e]
                + QW1[bt * 32 + 2 * m] * QW2[bt * 32 + 2 * n]
                + QW1[bt * 32 + 2 * m + 1] * QW2[bt * 32 + 2 * n + 1];
      if (m == n) val += QDD[bt * 16 + n];
      sH[tl * 256 + ((m >> 2) * 16 + n) * 4 + (m & 3)] = f2bf(val);
    }
    __syncthreads();
#pragma unroll
    for (int kk = 0; kk < 4; ++kk) {
      int idx = tid + kk * 256;
      int tl2 = idx >> 7, off = idx & 127;
      mqA[(((long long)(pass * 2 + b) * TT + t0 + tl2)) * 128 + off] =
          (uint)sH[tl2 * 256 + 2 * off] | ((uint)sH[tl2 * 256 + 2 * off + 1] << 16);
    }
  } else {
    // ---- kw pack -> kwsT2[(pass*2+b)*40 + j2][s] u32 pairs (pitch 1024) ----
    float (*sKW)[84] = (float (*)[84])sPool;
    const int bidx = g - 3072;                 // 64
    const int sch = bidx & 15, b = (bidx >> 4) & 1, pass = bidx >> 5;
    const int s0b = sch * 64;
    const float* KW1 = pass ? kw1_post : kw1_pre;
    const float* KW2 = pass ? kw2_post : kw2_pre;
    const float* KDD = pass ? kdd_post : kdd_pre;
#pragma unroll
    for (int k2 = 0; k2 < 5; ++k2) {
      int idx = tid + k2 * 256;
      int s = idx / 20, q4 = idx % 20;
      long long bs = (long long)b * TT + s0b + s;
      float4 vv; int dst;
      if (q4 < 8)       { vv = ((const float4*)(KW1 + bs * 32))[q4];      dst = q4 * 4; }
      else if (q4 < 16) { vv = ((const float4*)(KW2 + bs * 32))[q4 - 8];  dst = 32 + (q4 - 8) * 4; }
      else              { vv = ((const float4*)(KDD + bs * 16))[q4 - 16]; dst = 64 + (q4 - 16) * 4; }
      *(float4*)(&sKW[s][dst]) = vv;
    }
    __syncthreads();
#pragma unroll
    for (int k2 = 0; k2 < 10; ++k2) {
      int idx = tid + k2 * 256;
      int j2 = idx >> 6, s = idx & 63;
      uint pr = (uint)f2bf(sKW[s][2 * j2]) | ((uint)f2bf(sKW[s][2 * j2 + 1]) << 16);
      kwsT2[((long long)(pass * 2 + b) * 40 + j2) * 1024 + s0b + s] = pr;
    }
  }
}

// ---------- KB: MFMA-proj + softmax; wave = (t, half-band) ----------
__global__ __launch_bounds__(512, 2)
void kb_proj(const uint* __restrict__ mqA, const uint* __restrict__ kwsT2,
             ushort* __restrict__ S)
{
  const int tid = threadIdx.x;
  const int raw = blockIdx.x;                  // 512 = 8*64
  const int job = (raw & 7) * 64 + (raw >> 3);
  const int b = job >> 8, tq = job & 255;
  const int t0 = tq * 4;
  const int t32 = t0 & ~31;
  const int s0 = (t32 >= WIN) ? t32 - WIN : 0;
  const int lane = tid & 63, wv = tid >> 6;
  const int t = t0 + (wv & 3);
  const int half = wv >> 2;                    // 0: cols 0-143, 1: cols 144-287
  const int q = lane >> 4, cl = lane & 15;
  const int n0 = 4 * q;

  __shared__ uint skw[40][292];
  __shared__ float sZp[8][4][4];               // [wave][quad-group][j]

  s16x8 aPre, aPost;
  {
    uint2 a1 = *(const uint2*)(mqA + (((long long)b * TT + t) * 128) + lane * 2);
    uint2 a2 = *(const uint2*)(mqA + (((long long)(2 + b) * TT + t) * 128) + lane * 2);
    union { uint u[4]; s16x8 v; } pk;
    pk.u[0] = a1.x; pk.u[1] = a1.y; pk.u[2] = 0; pk.u[3] = 0; aPre = pk.v;
    pk.u[0] = a2.x; pk.u[1] = a2.y; aPost = pk.v;
  }

  const uint* kwb1 = kwsT2 + (long long)b * (40 * 1024);
  const uint* kwb2 = kwsT2 + (long long)(2 + b) * (40 * 1024);
#define STAGE(BASE)                                                          \
  { _Pragma("unroll") for (int i = 0; i < 6; ++i) {                          \
      int idx = tid + i * 512;                                               \
      if (idx < 2880) {                                                      \
        int j2 = idx / 72, s4 = idx % 72;                                    \
        uint4 vv = *(const uint4*)((BASE) + (long long)j2 * 1024 + s0 + s4 * 4); \
        *(uint4*)(&skw[j2][s4 * 4]) = vv; } } }

  STAGE(kwb1);
  __syncthreads();

  ushort* Sbt = S + (((long long)(b * TT + t)) * NH) * SW;
  uint usv[9][2];
  float zp[4] = {0.f, 0.f, 0.f, 0.f};

  // ================= PASS 1 =================
#pragma unroll
  for (int i = 0; i < 9; ++i) {
    const int gg = half * 9 + i;
    const int c = gg * 16 + cl;
    const int sg = s0 + c;
    ushort u0 = Sbt[(n0 + 0) * SW + c];
    ushort u1 = Sbt[(n0 + 1) * SW + c];
    ushort u2 = Sbt[(n0 + 2) * SW + c];
    ushort u3 = Sbt[(n0 + 3) * SW + c];
    union { uint u[4]; s16x8 v; } bf;
    bf.u[0] = (uint)u0 | ((uint)u1 << 16);
    bf.u[1] = (uint)u2 | ((uint)u3 << 16);
    bf.u[2] = 0; bf.u[3] = 0;
    f32x4 acc = {0.f, 0.f, 0.f, 0.f};
    acc = __builtin_amdgcn_mfma_f32_16x16x32_bf16(aPre, bf.v, acc, 0, 0, 0);
    float f0 = bf2f(u0), f1 = bf2f(u1), f2 = bf2f(u2), f3 = bf2f(u3);
    uint w0 = skw[n0 + 0][c], w1 = skw[n0 + 1][c], w2 = skw[n0 + 2][c], w3 = skw[n0 + 3][c];
    float hk0 = f0 * bflo(w0) + f1 * bflo(w1) + f2 * bflo(w2) + f3 * bflo(w3);
    float hk1 = f0 * bfhi(w0) + f1 * bfhi(w1) + f2 * bfhi(w2) + f3 * bfhi(w3);
    hk0 += __shfl_xor(hk0, 16); hk0 += __shfl_xor(hk0, 32);
    hk1 += __shfl_xor(hk1, 16); hk1 += __shfl_xor(hk1, 32);
    const bool valid = (sg <= t) && (sg + WIN > t);
    uint k20 = skw[16 + n0 + 0][c], k21 = skw[16 + n0 + 1][c];
    uint k22 = skw[16 + n0 + 2][c], k23 = skw[16 + n0 + 3][c];
    uint kd0 = skw[32 + 2 * q][c], kd1 = skw[32 + 2 * q + 1][c];
    float x0 = acc[0] + f0 + hk0 * bflo(k20) + hk1 * bfhi(k20) + f0 * bflo(kd0);
    float x1 = acc[1] + f1 + hk0 * bflo(k21) + hk1 * bfhi(k21) + f1 * bfhi(kd0);
    float x2 = acc[2] + f2 + hk0 * bflo(k22) + hk1 * bfhi(k22) + f2 * bflo(kd1);
    float x3 = acc[3] + f3 + hk0 * bflo(k23) + hk1 * bfhi(k23) + f3 * bfhi(kd1);
    float e0 = valid ? __expf(x0) : 0.f;
    float e1 = valid ? __expf(x1) : 0.f;
    float e2 = valid ? __expf(x2) : 0.f;
    float e3 = valid ? __expf(x3) : 0.f;
    zp[0] += e0; zp[1] += e1; zp[2] += e2; zp[3] += e3;
    usv[i][0] = (uint)f2bf(e0) | ((uint)f2bf(e1) << 16);
    usv[i][1] = (uint)f2bf(e2) | ((uint)f2bf(e3) << 16);
  }

  // ---- Z reduce per quad-group; combine half-band wave pair ----
#pragma unroll
  for (int j = 0; j < 4; ++j) {
    float z = zp[j];
    z += __shfl_xor(z, 1); z += __shfl_xor(z, 2);
    z += __shfl_xor(z, 4); z += __shfl_xor(z, 8);
    zp[j] = z;
  }
  if (cl == 0) {
#pragma unroll
    for (int j = 0; j < 4; ++j) sZp[wv][q][j] = zp[j];
  }
  __syncthreads();
  float rz[4];
#pragma unroll
  for (int j = 0; j < 4; ++j)
    rz[j] = 1.0f / (sZp[wv][q][j] + sZp[wv ^ 4][q][j]);
  STAGE(kwb2);
  __syncthreads();

  // ================= PASS 2 =================
#pragma unroll
  for (int i = 0; i < 9; ++i) {
    const int gg = half * 9 + i;
    const int c = gg * 16 + cl;
    float p0 = bflo(usv[i][0]) * rz[0];
    float p1 = bfhi(usv[i][0]) * rz[1];
    float p2 = bflo(usv[i][1]) * rz[2];
    float p3 = bfhi(usv[i][1]) * rz[3];
    union { uint u[4]; s16x8 v; } bf;
    bf.u[0] = (uint)f2bf(p0) | ((uint)f2bf(p1) << 16);
    bf.u[1] = (uint)f2bf(p2) | ((uint)f2bf(p3) << 16);
    bf.u[2] = 0; bf.u[3] = 0;
    f32x4 acc = {0.f, 0.f, 0.f, 0.f};
    acc = __builtin_amdgcn_mfma_f32_16x16x32_bf16(aPost, bf.v, acc, 0, 0, 0);
    uint w0 = skw[n0 + 0][c], w1 = skw[n0 + 1][c], w2 = skw[n0 + 2][c], w3 = skw[n0 + 3][c];
    float hk0 = p0 * bflo(w0) + p1 * bflo(w1) + p2 * bflo(w2) + p3 * bflo(w3);
    float hk1 = p0 * bfhi(w0) + p1 * bfhi(w1) + p2 * bfhi(w2) + p3 * bfhi(w3);
    hk0 += __shfl_xor(hk0, 16); hk0 += __shfl_xor(hk0, 32);
    hk1 += __shfl_xor(hk1, 16); hk1 += __shfl_xor(hk1, 32);
    uint k20 = skw[16 + n0 + 0][c], k21 = skw[16 + n0 + 1][c];
    uint k22 = skw[16 + n0 + 2][c], k23 = skw[16 + n0 + 3][c];
    uint kd0 = skw[32 + 2 * q][c], kd1 = skw[32 + 2 * q + 1][c];
    float x0 = acc[0] + p0 + hk0 * bflo(k20) + hk1 * bfhi(k20) + p0 * bflo(kd0);
    float x1 = acc[1] + p1 + hk0 * bflo(k21) + hk1 * bfhi(k21) + p1 * bfhi(kd0);
    float x2 = acc[2] + p2 + hk0 * bflo(k22) + hk1 * bfhi(k22) + p2 * bflo(kd1);
    float x3 = acc[3] + p3 + hk0 * bflo(k23) + hk1 * bfhi(k23) + p3 * bfhi(kd1);
    Sbt[(n0 + 0) * SW + c] = f2bf(x0);
    Sbt[(n0 + 1) * SW + c] = f2bf(x1);
    Sbt[(n0 + 2) * SW + c] = f2bf(x2);
    Sbt[(n0 + 3) * SW + c] = f2bf(x3);
  }
}

// ---------- KC: PV band GEMM per (b,h,32-t tile) ----------
__global__ __launch_bounds__(256, 4)
void kc_pv(const ushort* __restrict__ S, const ushort* __restrict__ v8,
           float* __restrict__ out)
{
  const int tid = threadIdx.x;
  const int raw = blockIdx.x;                  // 1024 = 8*128
  const int job = (raw & 7) * 128 + (raw >> 3);
  const int b = job >> 9, h = (job >> 5) & 15, tt = job & 31;
  const int t0 = tt * 32;
  const int s0 = (t0 >= WIN) ? t0 - WIN : 0;
  const int lane = tid & 63, wv = tid >> 6;

  __shared__ ushort sPt[32 * 296];

#pragma unroll
  for (int it = 0; it < 5; ++it) {
    int idx = tid + it * 256;
    if (idx < 32 * 36) {
      int r = idx / 36, sg = idx % 36;
      uint4 v = *(const uint4*)(S + (((long long)(b * TT + t0 + r)) * NH + h) * SW + sg * 8);
      *(uint4*)(&sPt[r * 296 + sg * 8]) = v;
    }
  }
  __syncthreads();

  const ushort* vbase = v8 + ((long long)(b * NH + h)) * (128 * DD * 8)
                           + ((long long)(s0 >> 3)) * (DD * 8);
  const int dcol = lane & 15, soct = lane >> 4;
  const int dt0 = wv * 2;
  f32x4 acc[2][2];
#pragma unroll
  for (int rt = 0; rt < 2; ++rt)
#pragma unroll
    for (int dd = 0; dd < 2; ++dd) acc[rt][dd] = (f32x4){0.f, 0.f, 0.f, 0.f};

#pragma unroll
  for (int ks = 0; ks < 9; ++ks) {
    s16x8 a0 = *(const s16x8*)(&sPt[(dcol) * 296 + ks * 32 + soct * 8]);
    s16x8 a1 = *(const s16x8*)(&sPt[(16 + dcol) * 296 + ks * 32 + soct * 8]);
#pragma unroll
    for (int dd = 0; dd < 2; ++dd) {
      s16x8 vb = *(const s16x8*)(vbase + (((long long)(ks * 4 + soct)) * DD + (dt0 + dd) * 16 + dcol) * 8);
      acc[0][dd] = __builtin_amdgcn_mfma_f32_16x16x32_bf16(a0, vb, acc[0][dd], 0, 0, 0);
      acc[1][dd] = __builtin_amdgcn_mfma_f32_16x16x32_bf16(a1, vb, acc[1][dd], 0, 0, 0);
    }
  }
  const int r0 = (lane >> 4) * 4;
#pragma unroll
  for (int rt = 0; rt < 2; ++rt)
#pragma unroll
    for (int dd = 0; dd < 2; ++dd)
#pragma unroll
      for (int j = 0; j < 4; ++j) {
        int trow = t0 + rt * 16 + r0 + j;
        out[(((long long)(b * TT + trow)) * NH + h) * DD + (dt0 + dd) * 16 + dcol] = acc[rt][dd][j];
      }
}

extern "C" void kernel_launch(void* const* d_in, const int* in_sizes, int n_in,
                              void* d_out, int out_size, void* d_ws, size_t ws_size,
                              hipStream_t stream) {
  const float* q        = (const float*)d_in[0];
  const float* k        = (const float*)d_in[1];
  const float* v        = (const float*)d_in[2];
  const float* w_pre    = (const float*)d_in[3];
  const float* w_post   = (const float*)d_in[4];
  const float* qw1_pre  = (const float*)d_in[5];
  const float* qw2_pre  = (const float*)d_in[6];
  const float* kw1_pre  = (const float*)d_in[7];
  const float* kw2_pre  = (const float*)d_in[8];
  const float* qw1_post = (const float*)d_in[9];
  const float* qw2_post = (const float*)d_in[10];
  const float* kw1_post = (const float*)d_in[11];
  const float* kw2_post = (const float*)d_in[12];
  const float* qdd_pre  = (const float*)d_in[13];
  const float* kdd_pre  = (const float*)d_in[14];
  const float* qdd_post = (const float*)d_in[15];
  const float* kdd_post = (const float*)d_in[16];
  float* out = (float*)d_out;

  // ws: kb8 8M | v8 8M | S 18M | mqA 2M | kwsT2 640K  (~37.5 MB)
  ushort* kb8   = (ushort*)d_ws;
  ushort* v8    = (ushort*)((char*)d_ws + 8388608ll);
  ushort* S     = (ushort*)((char*)d_ws + 16777216ll);
  uint*   mqA   = (uint*)  ((char*)d_ws + 35651584ll);
  uint*   kwsT2 = (uint*)  ((char*)d_ws + 37748736ll);

  prep1<<<512, 256, 0, stream>>>(k, kb8);
  ka_qk<<<3136, 256, 0, stream>>>(q, kb8, v,
                                  w_pre, w_post,
                                  qw1_pre, qw2_pre, qdd_pre, kw1_pre, kw2_pre, kdd_pre,
                                  qw1_post, qw2_post, qdd_post, kw1_post, kw2_post, kdd_post,
                                  S, v8, mqA, kwsT2);
  kb_proj<<<512, 512, 0, stream>>>(mqA, kwsT2, S);
  kc_pv  <<<1024, 256, 0, stream>>>(S, v8, out);
}

// Round 19
// 54.610 us; speedup vs baseline: 1.2685x; 1.0123x over previous
//
#include <hip/hip_runtime.h>

#define TT 1024
#define NH 16
#define DD 128
#define WIN 256
#define SW 288            // stored band width (18 x 16); S layout: [b][t][h][SW]
#define SCALE 0.08838834764831845f

typedef float f32x4 __attribute__((ext_vector_type(4)));
typedef short s16x8 __attribute__((ext_vector_type(8)));

__device__ __forceinline__ ushort f2bf(float x) {
  union { float f; unsigned u; } v; v.f = x;
  unsigned r = v.u + 0x7FFFu + ((v.u >> 16) & 1u);
  return (ushort)(r >> 16);
}
__device__ __forceinline__ float bf2f(ushort u) {
  union { unsigned u; float f; } v; v.u = ((unsigned)u) << 16; return v.f;
}
__device__ __forceinline__ float bflo(uint p) {
  union { unsigned u; float f; } v; v.u = p << 16; return v.f;
}
__device__ __forceinline__ float bfhi(uint p) {
  union { unsigned u; float f; } v; v.u = p & 0xFFFF0000u; return v.f;
}

// ---------- prep1: k -> bf16 [b][h][doct16][t][8] ----------
__global__ __launch_bounds__(256)
void prep1(const float* __restrict__ k, ushort* __restrict__ kb8)
{
  const int g = blockIdx.x;                    // 512
  const int tid = threadIdx.x;
  __shared__ float sPool[64 * 132];
  const int tt = g & 15, h = (g >> 4) & 15, b = g >> 8;
  const int t0 = tt * 64;
#pragma unroll
  for (int it = 0; it < 8; ++it) {
    int idx = tid + it * 256;
    int r = idx >> 5, cg = idx & 31;
    float4 x = *(const float4*)(k + (((long long)(b * TT + t0 + r)) * NH + h) * DD + cg * 4);
    *(float4*)(&sPool[r * 132 + cg * 4]) = x;
  }
  __syncthreads();
#pragma unroll
  for (int it = 0; it < 4; ++it) {
    int idx = tid + it * 256;
    int t = idx & 63, doct = idx >> 6;
    union { ushort u[8]; uint4 v; } pk;
#pragma unroll
    for (int e = 0; e < 8; ++e)
      pk.u[e] = f2bf(sPool[t * 132 + doct * 8 + e]);
    *(uint4*)(kb8 + ((((long long)(b * NH + h)) * 16 + doct) * TT + t0 + t) * 8) = pk.v;
  }
}

// ---------- KA+: 2048 QK | 1024 v8(32-row) | 512 mqA | 128 kw(32-s) ----------
// LDS pool shrunk to 19.2 KB -> 8 blocks/CU (32 waves, HW thread cap)
__global__ __launch_bounds__(256, 8)
void ka_qk(const float* __restrict__ q, const ushort* __restrict__ kb8,
           const float* __restrict__ v,
           const float* __restrict__ w_pre, const float* __restrict__ w_post,
           const float* __restrict__ qw1_pre, const float* __restrict__ qw2_pre,
           const float* __restrict__ qdd_pre,
           const float* __restrict__ kw1_pre, const float* __restrict__ kw2_pre,
           const float* __restrict__ kdd_pre,
           const float* __restrict__ qw1_post, const float* __restrict__ qw2_post,
           const float* __restrict__ qdd_post,
           const float* __restrict__ kw1_post, const float* __restrict__ kw2_post,
           const float* __restrict__ kdd_post,
           ushort* __restrict__ S, ushort* __restrict__ v8,
           uint* __restrict__ mqA, uint* __restrict__ kwsT2)
{
  const int g = blockIdx.x;                    // 3712
  const int tid = threadIdx.x;
  __shared__ float sPool[16 * 300];            // 19.2 KB shared by all branches

  if (g < 2048) {
    // ---- QK band GEMM per (b,h,16-t tile) -> S[b][t][h][*] bf16 ----
    float* strip = sPool;
    const int job = (g & 7) * 256 + (g >> 3);  // XCD swizzle
    const int b = job >> 10, h = (job >> 6) & 15, tt = job & 63;
    const int tlo = tt * 16;
    const int t32 = tlo & ~31;                 // S band base pinned to 32-t tile
    const int s0 = (t32 >= WIN) ? t32 - WIN : 0;
    const int lane = tid & 63, wv = tid >> 6;

    // stage 16 q rows (fp32, coalesced), build fragments w/ SCALE
    {
      const float* qsrc = q + (((long long)(b * TT + tlo)) * NH + h) * DD;
#pragma unroll
      for (int it = 0; it < 2; ++it) {
        int idx = tid + it * 256;              // 512 float4 = 16 rows x 32
        int r = idx >> 5, cg = idx & 31;
        float4 x = *(const float4*)(qsrc + (long long)r * (NH * DD) + cg * 4);
        *(float4*)(&sPool[r * 132 + cg * 4]) = x;
      }
    }
    __syncthreads();
    s16x8 qa[4];
    {
      const int ko = lane >> 4;
      const int rloc = lane & 15;
#pragma unroll
      for (int kk = 0; kk < 4; ++kk) {
        union { ushort u[8]; s16x8 v; } pk;
#pragma unroll
        for (int e = 0; e < 8; ++e)
          pk.u[e] = f2bf(sPool[rloc * 132 + kk * 32 + ko * 8 + e] * SCALE);
        qa[kk] = pk.v;
      }
    }
    __syncthreads();                           // sPool now free for strip

    const ushort* kbase = kb8 + ((long long)(b * NH + h)) * 16 * (TT * 8);

    int cl0 = tlo - (WIN - 1) - s0; if (cl0 < 0) cl0 = 0;
    const int chi = tlo + 15 - s0;
    const int stb = cl0 >> 4;
    const int nst = (chi >> 4) - stb + 1;
#pragma unroll 2
    for (int sti = wv; sti < nst; sti += 4) {
      const int cst = (stb + sti) * 16;
      const int scol = s0 + cst + (lane & 15);
      const int ko = lane >> 4;
      f32x4 acc = {0.f, 0.f, 0.f, 0.f};
#pragma unroll
      for (int kk = 0; kk < 4; ++kk) {
        s16x8 kb = *(const s16x8*)(kbase + ((long long)(kk * 4 + ko)) * (TT * 8) + scol * 8);
        acc = __builtin_amdgcn_mfma_f32_16x16x32_bf16(qa[kk], kb, acc, 0, 0, 0);
      }
      const int r0 = (lane >> 4) * 4;
#pragma unroll
      for (int j = 0; j < 4; ++j)
        strip[(r0 + j) * 300 + cst + (lane & 15)] = acc[j];
    }
    __syncthreads();
#pragma unroll
    for (int it = 0; it < 3; ++it) {
      int idx = tid + it * 256;
      if (idx < 16 * 36) {
        int r = idx / 36, sg = idx % 36;
        union { ushort u[8]; uint4 v; } pk;
#pragma unroll
        for (int e = 0; e < 8; ++e)
          pk.u[e] = f2bf(strip[r * 300 + sg * 8 + e]);
        *(uint4*)(S + (((long long)(b * TT + tlo + r)) * NH + h) * SW + sg * 8) = pk.v;
      }
    }
  } else if (g < 3072) {
    // ---- v fp32 -> v8 bf16 [b][h][soct128][d][8], 32-row tiles ----
    const int bidx = g - 2048;                 // 1024
    const int st = bidx & 31, h = (bidx >> 5) & 15, b = bidx >> 9;
    const int s0 = st * 32;
#pragma unroll
    for (int it = 0; it < 4; ++it) {
      int idx = tid + it * 256;                // 1024 f4 = 32 rows x 32
      int r = idx >> 5, cg = idx & 31;
      float4 x = *(const float4*)(v + (((long long)(b * TT + s0 + r)) * NH + h) * DD + cg * 4);
      *(float4*)(&sPool[r * 132 + cg * 4]) = x;
    }
    __syncthreads();
#pragma unroll
    for (int it = 0; it < 2; ++it) {
      int idx = tid + it * 256;                // 512 items: (so4 x d128)
      int d = idx & 127, so = idx >> 7;
      union { ushort u[8]; uint4 v; } pk;
#pragma unroll
      for (int e = 0; e < 8; ++e)
        pk.u[e] = f2bf(sPool[(so * 8 + e) * 132 + d]);
      *(uint4*)(v8 + ((((long long)(b * NH + h)) * 128 + st * 4 + so) * DD + d) * 8) = pk.v;
    }
  } else if (g < 3584) {
    // ---- mqA: (pass,b) x 8 t's. Mq_rest = W + qw1*qw2^T + diag(qdd) ----
    ushort* sH = (ushort*)sPool;               // [8][256] = 4 KB
    const int gg = g - 3072;
    const int tgrp = gg & 127, b = (gg >> 7) & 1, pass = gg >> 8;
    const int t0 = tgrp * 8;
    const float* W   = pass ? w_post   : w_pre;
    const float* QW1 = pass ? qw1_post : qw1_pre;
    const float* QW2 = pass ? qw2_post : qw2_pre;
    const float* QDD = pass ? qdd_post : qdd_pre;
    const int tl = tid >> 5, j = tid & 31;
    const long long bt = (long long)b * TT + t0 + tl;
#pragma unroll
    for (int ee = 0; ee < 8; ++ee) {
      int e = ee * 32 + j;
      int n = e & 15, m = e >> 4;
      float val = W[e]
                + QW1[bt * 32 + 2 * m] * QW2[bt * 32 + 2 * n]
                + QW1[bt * 32 + 2 * m + 1] * QW2[bt * 32 + 2 * n + 1];
      if (m == n) val += QDD[bt * 16 + n];
      sH[tl * 256 + ((m >> 2) * 16 + n) * 4 + (m & 3)] = f2bf(val);
    }
    __syncthreads();
#pragma unroll
    for (int kk = 0; kk < 4; ++kk) {
      int idx = tid + kk * 256;
      int tl2 = idx >> 7, off = idx & 127;
      mqA[(((long long)(pass * 2 + b) * TT + t0 + tl2)) * 128 + off] =
          (uint)sH[tl2 * 256 + 2 * off] | ((uint)sH[tl2 * 256 + 2 * off + 1] << 16);
    }
  } else {
    // ---- kw pack (32-s chunks) -> kwsT2[(pass*2+b)*40 + j2][s] u32 pairs ----
    float (*sKW)[84] = (float (*)[84])sPool;   // [32][84] = 10.5 KB
    const int bidx = g - 3584;                 // 128
    const int sch = bidx & 31, b = (bidx >> 5) & 1, pass = bidx >> 6;
    const int s0b = sch * 32;
    const float* KW1 = pass ? kw1_post : kw1_pre;
    const float* KW2 = pass ? kw2_post : kw2_pre;
    const float* KDD = pass ? kdd_post : kdd_pre;
#pragma unroll
    for (int k2 = 0; k2 < 3; ++k2) {
      int idx = tid + k2 * 256;                // 640 = 32 s * 20 f4
      if (idx < 640) {
        int s = idx / 20, q4 = idx % 20;
        long long bs = (long long)b * TT + s0b + s;
        float4 vv; int dst;
        if (q4 < 8)       { vv = ((const float4*)(KW1 + bs * 32))[q4];      dst = q4 * 4; }
        else if (q4 < 16) { vv = ((const float4*)(KW2 + bs * 32))[q4 - 8];  dst = 32 + (q4 - 8) * 4; }
        else              { vv = ((const float4*)(KDD + bs * 16))[q4 - 16]; dst = 64 + (q4 - 16) * 4; }
        *(float4*)(&sKW[s][dst]) = vv;
      }
    }
    __syncthreads();
#pragma unroll
    for (int k2 = 0; k2 < 5; ++k2) {
      int idx = tid + k2 * 256;                // 1280 = 40 j2 * 32 s
      int j2 = idx >> 5, s = idx & 31;
      uint pr = (uint)f2bf(sKW[s][2 * j2]) | ((uint)f2bf(sKW[s][2 * j2 + 1]) << 16);
      kwsT2[((long long)(pass * 2 + b) * 40 + j2) * 1024 + s0b + s] = pr;
    }
  }
}

// ---------- KB: MFMA-proj + softmax; wave = (t, half-band) ----------
__global__ __launch_bounds__(512, 2)
void kb_proj(const uint* __restrict__ mqA, const uint* __restrict__ kwsT2,
             ushort* __restrict__ S)
{
  const int tid = threadIdx.x;
  const int raw = blockIdx.x;                  // 512 = 8*64
  const int job = (raw & 7) * 64 + (raw >> 3);
  const int b = job >> 8, tq = job & 255;
  const int t0 = tq * 4;
  const int t32 = t0 & ~31;
  const int s0 = (t32 >= WIN) ? t32 - WIN : 0;
  const int lane = tid & 63, wv = tid >> 6;
  const int t = t0 + (wv & 3);
  const int half = wv >> 2;                    // 0: cols 0-143, 1: cols 144-287
  const int q = lane >> 4, cl = lane & 15;
  const int n0 = 4 * q;

  __shared__ uint skw[40][292];
  __shared__ float sZp[8][4][4];               // [wave][quad-group][j]

  s16x8 aPre, aPost;
  {
    uint2 a1 = *(const uint2*)(mqA + (((long long)b * TT + t) * 128) + lane * 2);
    uint2 a2 = *(const uint2*)(mqA + (((long long)(2 + b) * TT + t) * 128) + lane * 2);
    union { uint u[4]; s16x8 v; } pk;
    pk.u[0] = a1.x; pk.u[1] = a1.y; pk.u[2] = 0; pk.u[3] = 0; aPre = pk.v;
    pk.u[0] = a2.x; pk.u[1] = a2.y; aPost = pk.v;
  }

  const uint* kwb1 = kwsT2 + (long long)b * (40 * 1024);
  const uint* kwb2 = kwsT2 + (long long)(2 + b) * (40 * 1024);
#define STAGE(BASE)                                                          \
  { _Pragma("unroll") for (int i = 0; i < 6; ++i) {                          \
      int idx = tid + i * 512;                                               \
      if (idx < 2880) {                                                      \
        int j2 = idx / 72, s4 = idx % 72;                                    \
        uint4 vv = *(const uint4*)((BASE) + (long long)j2 * 1024 + s0 + s4 * 4); \
        *(uint4*)(&skw[j2][s4 * 4]) = vv; } } }

  STAGE(kwb1);
  __syncthreads();

  ushort* Sbt = S + (((long long)(b * TT + t)) * NH) * SW;
  uint usv[9][2];
  float zp[4] = {0.f, 0.f, 0.f, 0.f};

  // ================= PASS 1 =================
#pragma unroll
  for (int i = 0; i < 9; ++i) {
    const int gg = half * 9 + i;
    const int c = gg * 16 + cl;
    const int sg = s0 + c;
    ushort u0 = Sbt[(n0 + 0) * SW + c];
    ushort u1 = Sbt[(n0 + 1) * SW + c];
    ushort u2 = Sbt[(n0 + 2) * SW + c];
    ushort u3 = Sbt[(n0 + 3) * SW + c];
    union { uint u[4]; s16x8 v; } bf;
    bf.u[0] = (uint)u0 | ((uint)u1 << 16);
    bf.u[1] = (uint)u2 | ((uint)u3 << 16);
    bf.u[2] = 0; bf.u[3] = 0;
    f32x4 acc = {0.f, 0.f, 0.f, 0.f};
    acc = __builtin_amdgcn_mfma_f32_16x16x32_bf16(aPre, bf.v, acc, 0, 0, 0);
    float f0 = bf2f(u0), f1 = bf2f(u1), f2 = bf2f(u2), f3 = bf2f(u3);
    uint w0 = skw[n0 + 0][c], w1 = skw[n0 + 1][c], w2 = skw[n0 + 2][c], w3 = skw[n0 + 3][c];
    float hk0 = f0 * bflo(w0) + f1 * bflo(w1) + f2 * bflo(w2) + f3 * bflo(w3);
    float hk1 = f0 * bfhi(w0) + f1 * bfhi(w1) + f2 * bfhi(w2) + f3 * bfhi(w3);
    hk0 += __shfl_xor(hk0, 16); hk0 += __shfl_xor(hk0, 32);
    hk1 += __shfl_xor(hk1, 16); hk1 += __shfl_xor(hk1, 32);
    const bool valid = (sg <= t) && (sg + WIN > t);
    uint k20 = skw[16 + n0 + 0][c], k21 = skw[16 + n0 + 1][c];
    uint k22 = skw[16 + n0 + 2][c], k23 = skw[16 + n0 + 3][c];
    uint kd0 = skw[32 + 2 * q][c], kd1 = skw[32 + 2 * q + 1][c];
    float x0 = acc[0] + f0 + hk0 * bflo(k20) + hk1 * bfhi(k20) + f0 * bflo(kd0);
    float x1 = acc[1] + f1 + hk0 * bflo(k21) + hk1 * bfhi(k21) + f1 * bfhi(kd0);
    float x2 = acc[2] + f2 + hk0 * bflo(k22) + hk1 * bfhi(k22) + f2 * bflo(kd1);
    float x3 = acc[3] + f3 + hk0 * bflo(k23) + hk1 * bfhi(k23) + f3 * bfhi(kd1);
    float e0 = valid ? __expf(x0) : 0.f;
    float e1 = valid ? __expf(x1) : 0.f;
    float e2 = valid ? __expf(x2) : 0.f;
    float e3 = valid ? __expf(x3) : 0.f;
    zp[0] += e0; zp[1] += e1; zp[2] += e2; zp[3] += e3;
    usv[i][0] = (uint)f2bf(e0) | ((uint)f2bf(e1) << 16);
    usv[i][1] = (uint)f2bf(e2) | ((uint)f2bf(e3) << 16);
  }

  // ---- Z reduce per quad-group; combine half-band wave pair ----
#pragma unroll
  for (int j = 0; j < 4; ++j) {
    float z = zp[j];
    z += __shfl_xor(z, 1); z += __shfl_xor(z, 2);
    z += __shfl_xor(z, 4); z += __shfl_xor(z, 8);
    zp[j] = z;
  }
  if (cl == 0) {
#pragma unroll
    for (int j = 0; j < 4; ++j) sZp[wv][q][j] = zp[j];
  }
  __syncthreads();
  float rz[4];
#pragma unroll
  for (int j = 0; j < 4; ++j)
    rz[j] = 1.0f / (sZp[wv][q][j] + sZp[wv ^ 4][q][j]);
  STAGE(kwb2);
  __syncthreads();

  // ================= PASS 2 =================
#pragma unroll
  for (int i = 0; i < 9; ++i) {
    const int gg = half * 9 + i;
    const int c = gg * 16 + cl;
    float p0 = bflo(usv[i][0]) * rz[0];
    float p1 = bfhi(usv[i][0]) * rz[1];
    float p2 = bflo(usv[i][1]) * rz[2];
    float p3 = bfhi(usv[i][1]) * rz[3];
    union { uint u[4]; s16x8 v; } bf;
    bf.u[0] = (uint)f2bf(p0) | ((uint)f2bf(p1) << 16);
    bf.u[1] = (uint)f2bf(p2) | ((uint)f2bf(p3) << 16);
    bf.u[2] = 0; bf.u[3] = 0;
    f32x4 acc = {0.f, 0.f, 0.f, 0.f};
    acc = __builtin_amdgcn_mfma_f32_16x16x32_bf16(aPost, bf.v, acc, 0, 0, 0);
    uint w0 = skw[n0 + 0][c], w1 = skw[n0 + 1][c], w2 = skw[n0 + 2][c], w3 = skw[n0 + 3][c];
    float hk0 = p0 * bflo(w0) + p1 * bflo(w1) + p2 * bflo(w2) + p3 * bflo(w3);
    float hk1 = p0 * bfhi(w0) + p1 * bfhi(w1) + p2 * bfhi(w2) + p3 * bfhi(w3);
    hk0 += __shfl_xor(hk0, 16); hk0 += __shfl_xor(hk0, 32);
    hk1 += __shfl_xor(hk1, 16); hk1 += __shfl_xor(hk1, 32);
    uint k20 = skw[16 + n0 + 0][c], k21 = skw[16 + n0 + 1][c];
    uint k22 = skw[16 + n0 + 2][c], k23 = skw[16 + n0 + 3][c];
    uint kd0 = skw[32 + 2 * q][c], kd1 = skw[32 + 2 * q + 1][c];
    float x0 = acc[0] + p0 + hk0 * bflo(k20) + hk1 * bfhi(k20) + p0 * bflo(kd0);
    float x1 = acc[1] + p1 + hk0 * bflo(k21) + hk1 * bfhi(k21) + p1 * bfhi(kd0);
    float x2 = acc[2] + p2 + hk0 * bflo(k22) + hk1 * bfhi(k22) + p2 * bflo(kd1);
    float x3 = acc[3] + p3 + hk0 * bflo(k23) + hk1 * bfhi(k23) + p3 * bfhi(kd1);
    Sbt[(n0 + 0) * SW + c] = f2bf(x0);
    Sbt[(n0 + 1) * SW + c] = f2bf(x1);
    Sbt[(n0 + 2) * SW + c] = f2bf(x2);
    Sbt[(n0 + 3) * SW + c] = f2bf(x3);
  }
}

// ---------- KC: PV band GEMM per (b,h,32-t tile) ----------
__global__ __launch_bounds__(256, 4)
void kc_pv(const ushort* __restrict__ S, const ushort* __restrict__ v8,
           float* __restrict__ out)
{
  const int tid = threadIdx.x;
  const int raw = blockIdx.x;                  // 1024 = 8*128
  const int job = (raw & 7) * 128 + (raw >> 3);
  const int b = job >> 9, h = (job >> 5) & 15, tt = job & 31;
  const int t0 = tt * 32;
  const int s0 = (t0 >= WIN) ? t0 - WIN : 0;
  const int lane = tid & 63, wv = tid >> 6;

  __shared__ ushort sPt[32 * 296];

#pragma unroll
  for (int it = 0; it < 5; ++it) {
    int idx = tid + it * 256;
    if (idx < 32 * 36) {
      int r = idx / 36, sg = idx % 36;
      uint4 v = *(const uint4*)(S + (((long long)(b * TT + t0 + r)) * NH + h) * SW + sg * 8);
      *(uint4*)(&sPt[r * 296 + sg * 8]) = v;
    }
  }
  __syncthreads();

  const ushort* vbase = v8 + ((long long)(b * NH + h)) * (128 * DD * 8)
                           + ((long long)(s0 >> 3)) * (DD * 8);
  const int dcol = lane & 15, soct = lane >> 4;
  const int dt0 = wv * 2;
  f32x4 acc[2][2];
#pragma unroll
  for (int rt = 0; rt < 2; ++rt)
#pragma unroll
    for (int dd = 0; dd < 2; ++dd) acc[rt][dd] = (f32x4){0.f, 0.f, 0.f, 0.f};

#pragma unroll
  for (int ks = 0; ks < 9; ++ks) {
    s16x8 a0 = *(const s16x8*)(&sPt[(dcol) * 296 + ks * 32 + soct * 8]);
    s16x8 a1 = *(const s16x8*)(&sPt[(16 + dcol) * 296 + ks * 32 + soct * 8]);
#pragma unroll
    for (int dd = 0; dd < 2; ++dd) {
      s16x8 vb = *(const s16x8*)(vbase + (((long long)(ks * 4 + soct)) * DD + (dt0 + dd) * 16 + dcol) * 8);
      acc[0][dd] = __builtin_amdgcn_mfma_f32_16x16x32_bf16(a0, vb, acc[0][dd], 0, 0, 0);
      acc[1][dd] = __builtin_amdgcn_mfma_f32_16x16x32_bf16(a1, vb, acc[1][dd], 0, 0, 0);
    }
  }
  const int r0 = (lane >> 4) * 4;
#pragma unroll
  for (int rt = 0; rt < 2; ++rt)
#pragma unroll
    for (int dd = 0; dd < 2; ++dd)
#pragma unroll
      for (int j = 0; j < 4; ++j) {
        int trow = t0 + rt * 16 + r0 + j;
        out[(((long long)(b * TT + trow)) * NH + h) * DD + (dt0 + dd) * 16 + dcol] = acc[rt][dd][j];
      }
}

extern "C" void kernel_launch(void* const* d_in, const int* in_sizes, int n_in,
                              void* d_out, int out_size, void* d_ws, size_t ws_size,
                              hipStream_t stream) {
  const float* q        = (const float*)d_in[0];
  const float* k        = (const float*)d_in[1];
  const float* v        = (const float*)d_in[2];
  const float* w_pre    = (const float*)d_in[3];
  const float* w_post   = (const float*)d_in[4];
  const float* qw1_pre  = (const float*)d_in[5];
  const float* qw2_pre  = (const float*)d_in[6];
  const float* kw1_pre  = (const float*)d_in[7];
  const float* kw2_pre  = (const float*)d_in[8];
  const float* qw1_post = (const float*)d_in[9];
  const float* qw2_post = (const float*)d_in[10];
  const float* kw1_post = (const float*)d_in[11];
  const float* kw2_post = (const float*)d_in[12];
  const float* qdd_pre  = (const float*)d_in[13];
  const float* kdd_pre  = (const float*)d_in[14];
  const float* qdd_post = (const float*)d_in[15];
  const float* kdd_post = (const float*)d_in[16];
  float* out = (float*)d_out;

  // ws: kb8 8M | v8 8M | S 18M | mqA 2M | kwsT2 640K  (~37.5 MB)
  ushort* kb8   = (ushort*)d_ws;
  ushort* v8    = (ushort*)((char*)d_ws + 8388608ll);
  ushort* S     = (ushort*)((char*)d_ws + 16777216ll);
  uint*   mqA   = (uint*)  ((char*)d_ws + 35651584ll);
  uint*   kwsT2 = (uint*)  ((char*)d_ws + 37748736ll);

  prep1<<<512, 256, 0, stream>>>(k, kb8);
  ka_qk<<<3712, 256, 0, stream>>>(q, kb8, v,
                                  w_pre, w_post,
                                  qw1_pre, qw2_pre, qdd_pre, kw1_pre, kw2_pre, kdd_pre,
                                  qw1_post, qw2_post, qdd_post, kw1_post, kw2_post, kdd_post,
                                  S, v8, mqA, kwsT2);
  kb_proj<<<512, 512, 0, stream>>>(mqA, kwsT2, S);
  kc_pv  <<<1024, 256, 0, stream>>>(S, v8, out);
}

// Round 20
// 54.499 us; speedup vs baseline: 1.2710x; 1.0020x over previous
//
#include <hip/hip_runtime.h>

#define TT 1024
#define NH 16
#define DD 128
#define WIN 256
#define SW 288            // stored band width (18 x 16); S layout: [b][t][h][SW]
#define SCALE 0.08838834764831845f

typedef float f32x4 __attribute__((ext_vector_type(4)));
typedef short s16x8 __attribute__((ext_vector_type(8)));

__device__ __forceinline__ ushort f2bf(float x) {
  union { float f; unsigned u; } v; v.f = x;
  unsigned r = v.u + 0x7FFFu + ((v.u >> 16) & 1u);
  return (ushort)(r >> 16);
}
__device__ __forceinline__ float bf2f(ushort u) {
  union { unsigned u; float f; } v; v.u = ((unsigned)u) << 16; return v.f;
}
__device__ __forceinline__ float bflo(uint p) {
  union { unsigned u; float f; } v; v.u = p << 16; return v.f;
}
__device__ __forceinline__ float bfhi(uint p) {
  union { unsigned u; float f; } v; v.u = p & 0xFFFF0000u; return v.f;
}

// ---------- prep1: k -> bf16 [b][h][doct16][t][8] ----------
__global__ __launch_bounds__(256)
void prep1(const float* __restrict__ k, ushort* __restrict__ kb8)
{
  const int g = blockIdx.x;                    // 512
  const int tid = threadIdx.x;
  __shared__ float sPool[64 * 132];
  const int tt = g & 15, h = (g >> 4) & 15, b = g >> 8;
  const int t0 = tt * 64;
#pragma unroll
  for (int it = 0; it < 8; ++it) {
    int idx = tid + it * 256;
    int r = idx >> 5, cg = idx & 31;
    float4 x = *(const float4*)(k + (((long long)(b * TT + t0 + r)) * NH + h) * DD + cg * 4);
    *(float4*)(&sPool[r * 132 + cg * 4]) = x;
  }
  __syncthreads();
#pragma unroll
  for (int it = 0; it < 4; ++it) {
    int idx = tid + it * 256;
    int t = idx & 63, doct = idx >> 6;
    union { ushort u[8]; uint4 v; } pk;
#pragma unroll
    for (int e = 0; e < 8; ++e)
      pk.u[e] = f2bf(sPool[t * 132 + doct * 8 + e]);
    *(uint4*)(kb8 + ((((long long)(b * NH + h)) * 16 + doct) * TT + t0 + t) * 8) = pk.v;
  }
}

// ---------- KA+: 2048 QK | 1024 v8(32-row) | 512 mqA | 128 kw(32-s) ----------
__global__ __launch_bounds__(256, 8)
void ka_qk(const float* __restrict__ q, const ushort* __restrict__ kb8,
           const float* __restrict__ v,
           const float* __restrict__ w_pre, const float* __restrict__ w_post,
           const float* __restrict__ qw1_pre, const float* __restrict__ qw2_pre,
           const float* __restrict__ qdd_pre,
           const float* __restrict__ kw1_pre, const float* __restrict__ kw2_pre,
           const float* __restrict__ kdd_pre,
           const float* __restrict__ qw1_post, const float* __restrict__ qw2_post,
           const float* __restrict__ qdd_post,
           const float* __restrict__ kw1_post, const float* __restrict__ kw2_post,
           const float* __restrict__ kdd_post,
           ushort* __restrict__ S, ushort* __restrict__ v8,
           uint* __restrict__ mqA, uint* __restrict__ kwsT2)
{
  const int g = blockIdx.x;                    // 3712
  const int tid = threadIdx.x;
  __shared__ float sPool[16 * 300];            // 19.2 KB shared by all branches

  if (g < 2048) {
    // ---- QK band GEMM per (b,h,16-t tile) -> S[b][t][h][*] bf16 ----
    float* strip = sPool;
    const int job = (g & 7) * 256 + (g >> 3);  // XCD swizzle
    const int b = job >> 10, h = (job >> 6) & 15, tt = job & 63;
    const int tlo = tt * 16;
    const int t32 = tlo & ~31;                 // S band base pinned to 32-t tile
    const int s0 = (t32 >= WIN) ? t32 - WIN : 0;
    const int lane = tid & 63, wv = tid >> 6;

    {
      const float* qsrc = q + (((long long)(b * TT + tlo)) * NH + h) * DD;
#pragma unroll
      for (int it = 0; it < 2; ++it) {
        int idx = tid + it * 256;              // 512 float4 = 16 rows x 32
        int r = idx >> 5, cg = idx & 31;
        float4 x = *(const float4*)(qsrc + (long long)r * (NH * DD) + cg * 4);
        *(float4*)(&sPool[r * 132 + cg * 4]) = x;
      }
    }
    __syncthreads();
    s16x8 qa[4];
    {
      const int ko = lane >> 4;
      const int rloc = lane & 15;
#pragma unroll
      for (int kk = 0; kk < 4; ++kk) {
        union { ushort u[8]; s16x8 v; } pk;
#pragma unroll
        for (int e = 0; e < 8; ++e)
          pk.u[e] = f2bf(sPool[rloc * 132 + kk * 32 + ko * 8 + e] * SCALE);
        qa[kk] = pk.v;
      }
    }
    __syncthreads();                           // sPool now free for strip

    const ushort* kbase = kb8 + ((long long)(b * NH + h)) * 16 * (TT * 8);

    int cl0 = tlo - (WIN - 1) - s0; if (cl0 < 0) cl0 = 0;
    const int chi = tlo + 15 - s0;
    const int stb = cl0 >> 4;
    const int nst = (chi >> 4) - stb + 1;
#pragma unroll 2
    for (int sti = wv; sti < nst; sti += 4) {
      const int cst = (stb + sti) * 16;
      const int scol = s0 + cst + (lane & 15);
      const int ko = lane >> 4;
      f32x4 acc = {0.f, 0.f, 0.f, 0.f};
#pragma unroll
      for (int kk = 0; kk < 4; ++kk) {
        s16x8 kb = *(const s16x8*)(kbase + ((long long)(kk * 4 + ko)) * (TT * 8) + scol * 8);
        acc = __builtin_amdgcn_mfma_f32_16x16x32_bf16(qa[kk], kb, acc, 0, 0, 0);
      }
      const int r0 = (lane >> 4) * 4;
#pragma unroll
      for (int j = 0; j < 4; ++j)
        strip[(r0 + j) * 300 + cst + (lane & 15)] = acc[j];
    }
    __syncthreads();
#pragma unroll
    for (int it = 0; it < 3; ++it) {
      int idx = tid + it * 256;
      if (idx < 16 * 36) {
        int r = idx / 36, sg = idx % 36;
        union { ushort u[8]; uint4 v; } pk;
#pragma unroll
        for (int e = 0; e < 8; ++e)
          pk.u[e] = f2bf(strip[r * 300 + sg * 8 + e]);
        *(uint4*)(S + (((long long)(b * TT + tlo + r)) * NH + h) * SW + sg * 8) = pk.v;
      }
    }
  } else if (g < 3072) {
    // ---- v fp32 -> v8 bf16 [b][h][soct128][d][8], 32-row tiles ----
    const int bidx = g - 2048;                 // 1024
    const int st = bidx & 31, h = (bidx >> 5) & 15, b = bidx >> 9;
    const int s0 = st * 32;
#pragma unroll
    for (int it = 0; it < 4; ++it) {
      int idx = tid + it * 256;                // 1024 f4 = 32 rows x 32
      int r = idx >> 5, cg = idx & 31;
      float4 x = *(const float4*)(v + (((long long)(b * TT + s0 + r)) * NH + h) * DD + cg * 4);
      *(float4*)(&sPool[r * 132 + cg * 4]) = x;
    }
    __syncthreads();
#pragma unroll
    for (int it = 0; it < 2; ++it) {
      int idx = tid + it * 256;                // 512 items: (so4 x d128)
      int d = idx & 127, so = idx >> 7;
      union { ushort u[8]; uint4 v; } pk;
#pragma unroll
      for (int e = 0; e < 8; ++e)
        pk.u[e] = f2bf(sPool[(so * 8 + e) * 132 + d]);
      *(uint4*)(v8 + ((((long long)(b * NH + h)) * 128 + st * 4 + so) * DD + d) * 8) = pk.v;
    }
  } else if (g < 3584) {
    // ---- mqA: (pass,b) x 8 t's. Mq_rest = W + qw1*qw2^T + diag(qdd) ----
    ushort* sH = (ushort*)sPool;               // [8][256] = 4 KB
    const int gg = g - 3072;
    const int tgrp = gg & 127, b = (gg >> 7) & 1, pass = gg >> 8;
    const int t0 = tgrp * 8;
    const float* W   = pass ? w_post   : w_pre;
    const float* QW1 = pass ? qw1_post : qw1_pre;
    const float* QW2 = pass ? qw2_post : qw2_pre;
    const float* QDD = pass ? qdd_post : qdd_pre;
    const int tl = tid >> 5, j = tid & 31;
    const long long bt = (long long)b * TT + t0 + tl;
#pragma unroll
    for (int ee = 0; ee < 8; ++ee) {
      int e = ee * 32 + j;
      int n = e & 15, m = e >> 4;
      float val = W[e]
                + QW1[bt * 32 + 2 * m] * QW2[bt * 32 + 2 * n]
                + QW1[bt * 32 + 2 * m + 1] * QW2[bt * 32 + 2 * n + 1];
      if (m == n) val += QDD[bt * 16 + n];
      sH[tl * 256 + ((m >> 2) * 16 + n) * 4 + (m & 3)] = f2bf(val);
    }
    __syncthreads();
#pragma unroll
    for (int kk = 0; kk < 4; ++kk) {
      int idx = tid + kk * 256;
      int tl2 = idx >> 7, off = idx & 127;
      mqA[(((long long)(pass * 2 + b) * TT + t0 + tl2)) * 128 + off] =
          (uint)sH[tl2 * 256 + 2 * off] | ((uint)sH[tl2 * 256 + 2 * off + 1] << 16);
    }
  } else {
    // ---- kw pack (32-s chunks) -> kwsT2[(pass*2+b)*40 + j2][s] u32 pairs ----
    float (*sKW)[84] = (float (*)[84])sPool;   // [32][84] = 10.5 KB
    const int bidx = g - 3584;                 // 128
    const int sch = bidx & 31, b = (bidx >> 5) & 1, pass = bidx >> 6;
    const int s0b = sch * 32;
    const float* KW1 = pass ? kw1_post : kw1_pre;
    const float* KW2 = pass ? kw2_post : kw2_pre;
    const float* KDD = pass ? kdd_post : kdd_pre;
#pragma unroll
    for (int k2 = 0; k2 < 3; ++k2) {
      int idx = tid + k2 * 256;                // 640 = 32 s * 20 f4
      if (idx < 640) {
        int s = idx / 20, q4 = idx % 20;
        long long bs = (long long)b * TT + s0b + s;
        float4 vv; int dst;
        if (q4 < 8)       { vv = ((const float4*)(KW1 + bs * 32))[q4];      dst = q4 * 4; }
        else if (q4 < 16) { vv = ((const float4*)(KW2 + bs * 32))[q4 - 8];  dst = 32 + (q4 - 8) * 4; }
        else              { vv = ((const float4*)(KDD + bs * 16))[q4 - 16]; dst = 64 + (q4 - 16) * 4; }
        *(float4*)(&sKW[s][dst]) = vv;
      }
    }
    __syncthreads();
#pragma unroll
    for (int k2 = 0; k2 < 5; ++k2) {
      int idx = tid + k2 * 256;                // 1280 = 40 j2 * 32 s
      int j2 = idx >> 5, s = idx & 31;
      uint pr = (uint)f2bf(sKW[s][2 * j2]) | ((uint)f2bf(sKW[s][2 * j2 + 1]) << 16);
      kwsT2[((long long)(pass * 2 + b) * 40 + j2) * 1024 + s0b + s] = pr;
    }
  }
}

// ---------- KB: MFMA-proj + softmax; wave = (t, half-band); 2 blocks/CU ----------
__global__ __launch_bounds__(512, 4)
void kb_proj(const uint* __restrict__ mqA, const uint* __restrict__ kwsT2,
             ushort* __restrict__ S)
{
  const int tid = threadIdx.x;
  const int raw = blockIdx.x;                  // 512 = 8*64
  const int job = (raw & 7) * 64 + (raw >> 3);
  const int b = job >> 8, tq = job & 255;
  const int t0 = tq * 4;
  const int t32 = t0 & ~31;
  const int s0 = (t32 >= WIN) ? t32 - WIN : 0;
  const int lane = tid & 63, wv = tid >> 6;
  const int t = t0 + (wv & 3);
  const int half = wv >> 2;                    // 0: cols 0-143, 1: cols 144-287
  const int q = lane >> 4, cl = lane & 15;
  const int n0 = 4 * q;

  __shared__ uint skw[40][292];
  __shared__ float sZp[8][4][4];               // [wave][quad-group][j]

  s16x8 aPre, aPost;
  {
    uint2 a1 = *(const uint2*)(mqA + (((long long)b * TT + t) * 128) + lane * 2);
    uint2 a2 = *(const uint2*)(mqA + (((long long)(2 + b) * TT + t) * 128) + lane * 2);
    union { uint u[4]; s16x8 v; } pk;
    pk.u[0] = a1.x; pk.u[1] = a1.y; pk.u[2] = 0; pk.u[3] = 0; aPre = pk.v;
    pk.u[0] = a2.x; pk.u[1] = a2.y; aPost = pk.v;
  }

  const uint* kwb1 = kwsT2 + (long long)b * (40 * 1024);
  const uint* kwb2 = kwsT2 + (long long)(2 + b) * (40 * 1024);
#define STAGE(BASE)                                                          \
  { _Pragma("unroll") for (int i = 0; i < 6; ++i) {                          \
      int idx = tid + i * 512;                                               \
      if (idx < 2880) {                                                      \
        int j2 = idx / 72, s4 = idx % 72;                                    \
        uint4 vv = *(const uint4*)((BASE) + (long long)j2 * 1024 + s0 + s4 * 4); \
        *(uint4*)(&skw[j2][s4 * 4]) = vv; } } }

  STAGE(kwb1);
  __syncthreads();

  ushort* Sbt = S + (((long long)(b * TT + t)) * NH) * SW;
  uint usv[9][2];
  float zp[4] = {0.f, 0.f, 0.f, 0.f};

  // ================= PASS 1 =================
#pragma unroll
  for (int i = 0; i < 9; ++i) {
    const int gg = half * 9 + i;
    const int c = gg * 16 + cl;
    const int sg = s0 + c;
    ushort u0 = Sbt[(n0 + 0) * SW + c];
    ushort u1 = Sbt[(n0 + 1) * SW + c];
    ushort u2 = Sbt[(n0 + 2) * SW + c];
    ushort u3 = Sbt[(n0 + 3) * SW + c];
    union { uint u[4]; s16x8 v; } bf;
    bf.u[0] = (uint)u0 | ((uint)u1 << 16);
    bf.u[1] = (uint)u2 | ((uint)u3 << 16);
    bf.u[2] = 0; bf.u[3] = 0;
    f32x4 acc = {0.f, 0.f, 0.f, 0.f};
    acc = __builtin_amdgcn_mfma_f32_16x16x32_bf16(aPre, bf.v, acc, 0, 0, 0);
    float f0 = bf2f(u0), f1 = bf2f(u1), f2 = bf2f(u2), f3 = bf2f(u3);
    uint w0 = skw[n0 + 0][c], w1 = skw[n0 + 1][c], w2 = skw[n0 + 2][c], w3 = skw[n0 + 3][c];
    float hk0 = f0 * bflo(w0) + f1 * bflo(w1) + f2 * bflo(w2) + f3 * bflo(w3);
    float hk1 = f0 * bfhi(w0) + f1 * bfhi(w1) + f2 * bfhi(w2) + f3 * bfhi(w3);
    hk0 += __shfl_xor(hk0, 16); hk0 += __shfl_xor(hk0, 32);
    hk1 += __shfl_xor(hk1, 16); hk1 += __shfl_xor(hk1, 32);
    const bool valid = (sg <= t) && (sg + WIN > t);
    uint k20 = skw[16 + n0 + 0][c], k21 = skw[16 + n0 + 1][c];
    uint k22 = skw[16 + n0 + 2][c], k23 = skw[16 + n0 + 3][c];
    uint kd0 = skw[32 + 2 * q][c], kd1 = skw[32 + 2 * q + 1][c];
    float x0 = acc[0] + f0 + hk0 * bflo(k20) + hk1 * bfhi(k20) + f0 * bflo(kd0);
    float x1 = acc[1] + f1 + hk0 * bflo(k21) + hk1 * bfhi(k21) + f1 * bfhi(kd0);
    float x2 = acc[2] + f2 + hk0 * bflo(k22) + hk1 * bfhi(k22) + f2 * bflo(kd1);
    float x3 = acc[3] + f3 + hk0 * bflo(k23) + hk1 * bfhi(k23) + f3 * bfhi(kd1);
    float e0 = valid ? __expf(x0) : 0.f;
    float e1 = valid ? __expf(x1) : 0.f;
    float e2 = valid ? __expf(x2) : 0.f;
    float e3 = valid ? __expf(x3) : 0.f;
    zp[0] += e0; zp[1] += e1; zp[2] += e2; zp[3] += e3;
    usv[i][0] = (uint)f2bf(e0) | ((uint)f2bf(e1) << 16);
    usv[i][1] = (uint)f2bf(e2) | ((uint)f2bf(e3) << 16);
  }

  // ---- Z reduce per quad-group; combine half-band wave pair ----
#pragma unroll
  for (int j = 0; j < 4; ++j) {
    float z = zp[j];
    z += __shfl_xor(z, 1); z += __shfl_xor(z, 2);
    z += __shfl_xor(z, 4); z += __shfl_xor(z, 8);
    zp[j] = z;
  }
  if (cl == 0) {
#pragma unroll
    for (int j = 0; j < 4; ++j) sZp[wv][q][j] = zp[j];
  }
  __syncthreads();
  float rz[4];
#pragma unroll
  for (int j = 0; j < 4; ++j)
    rz[j] = 1.0f / (sZp[wv][q][j] + sZp[wv ^ 4][q][j]);
  STAGE(kwb2);
  __syncthreads();

  // ================= PASS 2 =================
#pragma unroll
  for (int i = 0; i < 9; ++i) {
    const int gg = half * 9 + i;
    const int c = gg * 16 + cl;
    float p0 = bflo(usv[i][0]) * rz[0];
    float p1 = bfhi(usv[i][0]) * rz[1];
    float p2 = bflo(usv[i][1]) * rz[2];
    float p3 = bfhi(usv[i][1]) * rz[3];
    union { uint u[4]; s16x8 v; } bf;
    bf.u[0] = (uint)f2bf(p0) | ((uint)f2bf(p1) << 16);
    bf.u[1] = (uint)f2bf(p2) | ((uint)f2bf(p3) << 16);
    bf.u[2] = 0; bf.u[3] = 0;
    f32x4 acc = {0.f, 0.f, 0.f, 0.f};
    acc = __builtin_amdgcn_mfma_f32_16x16x32_bf16(aPost, bf.v, acc, 0, 0, 0);
    uint w0 = skw[n0 + 0][c], w1 = skw[n0 + 1][c], w2 = skw[n0 + 2][c], w3 = skw[n0 + 3][c];
    float hk0 = p0 * bflo(w0) + p1 * bflo(w1) + p2 * bflo(w2) + p3 * bflo(w3);
    float hk1 = p0 * bfhi(w0) + p1 * bfhi(w1) + p2 * bfhi(w2) + p3 * bfhi(w3);
    hk0 += __shfl_xor(hk0, 16); hk0 += __shfl_xor(hk0, 32);
    hk1 += __shfl_xor(hk1, 16); hk1 += __shfl_xor(hk1, 32);
    uint k20 = skw[16 + n0 + 0][c], k21 = skw[16 + n0 + 1][c];
    uint k22 = skw[16 + n0 + 2][c], k23 = skw[16 + n0 + 3][c];
    uint kd0 = skw[32 + 2 * q][c], kd1 = skw[32 + 2 * q + 1][c];
    float x0 = acc[0] + p0 + hk0 * bflo(k20) + hk1 * bfhi(k20) + p0 * bflo(kd0);
    float x1 = acc[1] + p1 + hk0 * bflo(k21) + hk1 * bfhi(k21) + p1 * bfhi(kd0);
    float x2 = acc[2] + p2 + hk0 * bflo(k22) + hk1 * bfhi(k22) + p2 * bflo(kd1);
    float x3 = acc[3] + p3 + hk0 * bflo(k23) + hk1 * bfhi(k23) + p3 * bfhi(kd1);
    Sbt[(n0 + 0) * SW + c] = f2bf(x0);
    Sbt[(n0 + 1) * SW + c] = f2bf(x1);
    Sbt[(n0 + 2) * SW + c] = f2bf(x2);
    Sbt[(n0 + 3) * SW + c] = f2bf(x3);
  }
}

// ---------- KC: PV band GEMM per (b,h,32-t tile); 8 blocks/CU ----------
__global__ __launch_bounds__(256, 8)
void kc_pv(const ushort* __restrict__ S, const ushort* __restrict__ v8,
           float* __restrict__ out)
{
  const int tid = threadIdx.x;
  const int raw = blockIdx.x;                  // 1024 = 8*128
  const int job = (raw & 7) * 128 + (raw >> 3);
  const int b = job >> 9, h = (job >> 5) & 15, tt = job & 31;
  const int t0 = tt * 32;
  const int s0 = (t0 >= WIN) ? t0 - WIN : 0;
  const int lane = tid & 63, wv = tid >> 6;

  __shared__ ushort sPt[32 * 296];

#pragma unroll
  for (int it = 0; it < 5; ++it) {
    int idx = tid + it * 256;
    if (idx < 32 * 36) {
      int r = idx / 36, sg = idx % 36;
      uint4 v = *(const uint4*)(S + (((long long)(b * TT + t0 + r)) * NH + h) * SW + sg * 8);
      *(uint4*)(&sPt[r * 296 + sg * 8]) = v;
    }
  }
  __syncthreads();

  const ushort* vbase = v8 + ((long long)(b * NH + h)) * (128 * DD * 8)
                           + ((long long)(s0 >> 3)) * (DD * 8);
  const int dcol = lane & 15, soct = lane >> 4;
  const int dt0 = wv * 2;
  f32x4 acc[2][2];
#pragma unroll
  for (int rt = 0; rt < 2; ++rt)
#pragma unroll
    for (int dd = 0; dd < 2; ++dd) acc[rt][dd] = (f32x4){0.f, 0.f, 0.f, 0.f};

#pragma unroll
  for (int ks = 0; ks < 9; ++ks) {
    s16x8 a0 = *(const s16x8*)(&sPt[(dcol) * 296 + ks * 32 + soct * 8]);
    s16x8 a1 = *(const s16x8*)(&sPt[(16 + dcol) * 296 + ks * 32 + soct * 8]);
#pragma unroll
    for (int dd = 0; dd < 2; ++dd) {
      s16x8 vb = *(const s16x8*)(vbase + (((long long)(ks * 4 + soct)) * DD + (dt0 + dd) * 16 + dcol) * 8);
      acc[0][dd] = __builtin_amdgcn_mfma_f32_16x16x32_bf16(a0, vb, acc[0][dd], 0, 0, 0);
      acc[1][dd] = __builtin_amdgcn_mfma_f32_16x16x32_bf16(a1, vb, acc[1][dd], 0, 0, 0);
    }
  }
  const int r0 = (lane >> 4) * 4;
#pragma unroll
  for (int rt = 0; rt < 2; ++rt)
#pragma unroll
    for (int dd = 0; dd < 2; ++dd)
#pragma unroll
      for (int j = 0; j < 4; ++j) {
        int trow = t0 + rt * 16 + r0 + j;
        out[(((long long)(b * TT + trow)) * NH + h) * DD + (dt0 + dd) * 16 + dcol] = acc[rt][dd][j];
      }
}

extern "C" void kernel_launch(void* const* d_in, const int* in_sizes, int n_in,
                              void* d_out, int out_size, void* d_ws, size_t ws_size,
                              hipStream_t stream) {
  const float* q        = (const float*)d_in[0];
  const float* k        = (const float*)d_in[1];
  const float* v        = (const float*)d_in[2];
  const float* w_pre    = (const float*)d_in[3];
  const float* w_post   = (const float*)d_in[4];
  const float* qw1_pre  = (const float*)d_in[5];
  const float* qw2_pre  = (const float*)d_in[6];
  const float* kw1_pre  = (const float*)d_in[7];
  const float* kw2_pre  = (const float*)d_in[8];
  const float* qw1_post = (const float*)d_in[9];
  const float* qw2_post = (const float*)d_in[10];
  const float* kw1_post = (const float*)d_in[11];
  const float* kw2_post = (const float*)d_in[12];
  const float* qdd_pre  = (const float*)d_in[13];
  const float* kdd_pre  = (const float*)d_in[14];
  const float* qdd_post = (const float*)d_in[15];
  const float* kdd_post = (const float*)d_in[16];
  float* out = (float*)d_out;

  // ws: kb8 8M | v8 8M | S 18M | mqA 2M | kwsT2 640K  (~37.5 MB)
  ushort* kb8   = (ushort*)d_ws;
  ushort* v8    = (ushort*)((char*)d_ws + 8388608ll);
  ushort* S     = (ushort*)((char*)d_ws + 16777216ll);
  uint*   mqA   = (uint*)  ((char*)d_ws + 35651584ll);
  uint*   kwsT2 = (uint*)  ((char*)d_ws + 37748736ll);

  prep1<<<512, 256, 0, stream>>>(k, kb8);
  ka_qk<<<3712, 256, 0, stream>>>(q, kb8, v,
                                  w_pre, w_post,
                                  qw1_pre, qw2_pre, qdd_pre, kw1_pre, kw2_pre, kdd_pre,
                                  qw1_post, qw2_post, qdd_post, kw1_post, kw2_post, kdd_post,
                                  S, v8, mqA, kwsT2);
  kb_proj<<<512, 512, 0, stream>>>(mqA, kwsT2, S);
  kc_pv  <<<1024, 256, 0, stream>>>(S, v8, out);
}